// Round 1
// baseline (9150.738 us; speedup 1.0000x reference)
//
#include <hip/hip_runtime.h>
#include <hip/hip_bf16.h>
#include <math.h>

#define L_ 6
#define D_ 768
#define H_ 12
#define DK_ 64
#define DFF_ 3072
#define VOCAB_ 32128
#define NB_ 32
#define MAXDIST_ 128
#define B_ 8
#define S_ 512
#define NEG_ (-1e9f)
#define BS_ (B_*S_)          // 4096 rows
#define BSD_ ((size_t)BS_*D_) // 3,145,728 floats

// ---------------- embedding gather ----------------
__global__ __launch_bounds__(192) void k_embed(const int* __restrict__ ids,
                                               const float* __restrict__ ew,
                                               float* __restrict__ h) {
    int row = blockIdx.x;                  // 0..4095
    int id = ids[row];
    const float4* src = (const float4*)(ew + (size_t)id * D_);
    float4* dst = (float4*)(h + (size_t)row * D_);
    dst[threadIdx.x] = src[threadIdx.x];   // 192 float4 = 768 floats
}

// ---------------- T5 RMSNorm ----------------
__global__ __launch_bounds__(256) void k_rmsnorm(const float* __restrict__ in,
                                                 const float* __restrict__ w,
                                                 float* __restrict__ out) {
    int row = blockIdx.x;
    int tid = threadIdx.x;
    const float* x = in + (size_t)row * D_;
    float ss = 0.f;
    for (int i = tid; i < D_; i += 256) { float v = x[i]; ss += v * v; }
    #pragma unroll
    for (int off = 32; off; off >>= 1) ss += __shfl_down(ss, off, 64);
    __shared__ float sbuf[4];
    if ((tid & 63) == 0) sbuf[tid >> 6] = ss;
    __syncthreads();
    float tot = sbuf[0] + sbuf[1] + sbuf[2] + sbuf[3];
    float scale = rsqrtf(tot / (float)D_ + 1e-6f);
    float* o = out + (size_t)row * D_;
    for (int i = tid; i < D_; i += 256) o[i] = w[i] * x[i] * scale;
}

// ---------------- relative position bias (transposed: [h][key][q]) ----------------
__global__ __launch_bounds__(256) void k_posbias(const float* __restrict__ rbw,
                                                 float* __restrict__ biasT) {
    int idx = blockIdx.x * 256 + threadIdx.x;   // over S*S
    if (idx >= S_ * S_) return;
    int key = idx / S_, qi = idx - key * S_;
    int rel = key - qi;                          // memory - query
    const int nb = NB_ / 2;                      // 16
    int ret = rel > 0 ? nb : 0;
    int n = rel < 0 ? -rel : rel;
    const int max_exact = nb / 2;                // 8
    int val;
    if (n < max_exact) {
        val = n;
    } else {
        float lf = logf((float)n / (float)max_exact) /
                   logf((float)MAXDIST_ / (float)max_exact) * (float)(nb - max_exact);
        val = max_exact + (int)lf;               // trunc toward zero; lf >= 0 here
        if (val > nb - 1) val = nb - 1;
    }
    int bucket = ret + val;
    #pragma unroll
    for (int hh = 0; hh < H_; ++hh)
        biasT[((size_t)hh * S_ + key) * S_ + qi] = rbw[bucket * H_ + hh];
}

// ---------------- tiled fp32 NT GEMM:  C[m,n] = sum_k A[m,k]*B[n,k] (+res)(+relu) ----------------
__device__ __forceinline__ void gemm_body(const float* __restrict__ A,
                                          const float* __restrict__ Bm,
                                          const float* __restrict__ res,
                                          float* __restrict__ C,
                                          int N, int K, int bm, int bn, bool relu) {
    __shared__ float As[8][132];
    __shared__ float Bs[8][132];
    int t = threadIdx.x;
    int tx = t & 15, ty = t >> 4;
    int arow = t >> 1;
    int ac4 = (t & 1) * 4;
    const float* Ap = A + (size_t)(bm * 128 + arow) * K + ac4;
    const float* Bp = Bm + (size_t)(bn * 128 + arow) * K + ac4;
    float acc[8][8] = {};
    for (int k0 = 0; k0 < K; k0 += 8) {
        float4 av = *(const float4*)(Ap + k0);
        float4 bv = *(const float4*)(Bp + k0);
        __syncthreads();
        As[ac4 + 0][arow] = av.x; As[ac4 + 1][arow] = av.y;
        As[ac4 + 2][arow] = av.z; As[ac4 + 3][arow] = av.w;
        Bs[ac4 + 0][arow] = bv.x; Bs[ac4 + 1][arow] = bv.y;
        Bs[ac4 + 2][arow] = bv.z; Bs[ac4 + 3][arow] = bv.w;
        __syncthreads();
        #pragma unroll
        for (int kk = 0; kk < 8; ++kk) {
            float a[8], b[8];
            #pragma unroll
            for (int i = 0; i < 8; ++i) a[i] = As[kk][i * 16 + ty];
            #pragma unroll
            for (int j = 0; j < 8; ++j) b[j] = Bs[kk][j * 16 + tx];
            #pragma unroll
            for (int i = 0; i < 8; ++i)
                #pragma unroll
                for (int j = 0; j < 8; ++j)
                    acc[i][j] = fmaf(a[i], b[j], acc[i][j]);
        }
    }
    #pragma unroll
    for (int i = 0; i < 8; ++i) {
        int row = bm * 128 + i * 16 + ty;
        #pragma unroll
        for (int j = 0; j < 8; ++j) {
            int col = bn * 128 + j * 16 + tx;
            float v = acc[i][j];
            if (res)  v += res[(size_t)row * N + col];
            if (relu) v = fmaxf(v, 0.f);
            C[(size_t)row * N + col] = v;
        }
    }
}

template<bool RELU>
__global__ __launch_bounds__(256) void k_gemm(const float* __restrict__ A,
                                              const float* __restrict__ Bm,
                                              const float* __restrict__ res,
                                              float* __restrict__ C,
                                              int N, int K) {
    gemm_body(A, Bm, res, C, N, K, blockIdx.x, blockIdx.y, RELU);
}

__global__ __launch_bounds__(256) void k_gemm_qkv(const float* __restrict__ X,
                                                  const float* __restrict__ qw,
                                                  const float* __restrict__ kw,
                                                  const float* __restrict__ vw,
                                                  float* __restrict__ qo,
                                                  float* __restrict__ ko,
                                                  float* __restrict__ vo) {
    const float* Bm = blockIdx.z == 0 ? qw : (blockIdx.z == 1 ? kw : vw);
    float* C       = blockIdx.z == 0 ? qo : (blockIdx.z == 1 ? ko : vo);
    gemm_body(X, Bm, nullptr, C, D_, D_, blockIdx.x, blockIdx.y, false);
}

// ---------------- attention: 1 thread = 1 query row, online softmax ----------------
__global__ __launch_bounds__(128) void k_attn(const float* __restrict__ qb,
                                              const float* __restrict__ kb,
                                              const float* __restrict__ vb,
                                              const float* __restrict__ biasT,
                                              const float* __restrict__ mask,
                                              float* __restrict__ ctx) {
    __shared__ float Ks[64][64];
    __shared__ float Vs[64][64];
    int bh = blockIdx.x;
    int b = bh / H_, hh = bh - b * H_;
    int t = threadIdx.x;
    int qi = blockIdx.y * 128 + t;

    float qreg[64];
    {
        const float4* qp = (const float4*)(qb + ((size_t)(b * S_ + qi)) * D_ + hh * DK_);
        #pragma unroll
        for (int i = 0; i < 16; ++i) {
            float4 u = qp[i];
            qreg[4*i] = u.x; qreg[4*i+1] = u.y; qreg[4*i+2] = u.z; qreg[4*i+3] = u.w;
        }
    }
    float m = -3.0e38f, l = 0.f;
    float acc[64];
    #pragma unroll
    for (int d = 0; d < 64; ++d) acc[d] = 0.f;

    for (int kt = 0; kt < S_ / 64; ++kt) {
        __syncthreads();
        const float4* ksrc = (const float4*)(kb + ((size_t)(b * S_ + kt * 64)) * D_ + hh * DK_);
        const float4* vsrc = (const float4*)(vb + ((size_t)(b * S_ + kt * 64)) * D_ + hh * DK_);
        #pragma unroll
        for (int i = 0; i < 8; ++i) {
            int f = i * 128 + t;
            int row = f >> 4, c4 = f & 15;
            *(float4*)&Ks[row][c4 * 4] = ksrc[(size_t)row * (D_ / 4) + c4];
            *(float4*)&Vs[row][c4 * 4] = vsrc[(size_t)row * (D_ / 4) + c4];
        }
        __syncthreads();
        const float* bT = biasT + ((size_t)hh * S_ + kt * 64) * S_ + qi;
        const float* mp = mask + b * S_ + kt * 64;
        for (int j = 0; j < 64; ++j) {
            float s = 0.f;
            #pragma unroll
            for (int d = 0; d < 64; ++d) s = fmaf(qreg[d], Ks[j][d], s);
            s += bT[(size_t)j * S_];
            s += (1.f - mp[j]) * NEG_;
            if (s <= m) {
                float p = __expf(s - m);
                l += p;
                #pragma unroll
                for (int d = 0; d < 64; ++d) acc[d] = fmaf(p, Vs[j][d], acc[d]);
            } else {
                float sc = __expf(m - s);
                l = fmaf(l, sc, 1.f);
                #pragma unroll
                for (int d = 0; d < 64; ++d) acc[d] = fmaf(acc[d], sc, Vs[j][d]);
                m = s;
            }
        }
    }
    float inv = 1.f / l;
    float* op = ctx + ((size_t)(b * S_ + qi)) * D_ + hh * DK_;
    #pragma unroll
    for (int i = 0; i < 16; ++i) {
        float4 u;
        u.x = acc[4*i] * inv; u.y = acc[4*i+1] * inv;
        u.z = acc[4*i+2] * inv; u.w = acc[4*i+3] * inv;
        *(float4*)(op + 4 * i) = u;
    }
}

// ---------------- launcher ----------------
extern "C" void kernel_launch(void* const* d_in, const int* in_sizes, int n_in,
                              void* d_out, int out_size, void* d_ws, size_t ws_size,
                              hipStream_t stream) {
    const int*   ids  = (const int*)d_in[0];
    const float* mask = (const float*)d_in[1];
    const float* ew   = (const float*)d_in[2];
    const float* ln1  = (const float*)d_in[3];
    const float* qw   = (const float*)d_in[4];
    const float* kw   = (const float*)d_in[5];
    const float* vw   = (const float*)d_in[6];
    const float* rbw  = (const float*)d_in[7];
    const float* ow   = (const float*)d_in[8];
    const float* ln2  = (const float*)d_in[9];
    const float* wiw  = (const float*)d_in[10];
    const float* wow  = (const float*)d_in[11];
    const float* flnw = (const float*)d_in[12];
    float* out = (float*)d_out;
    float* ws  = (float*)d_ws;

    // ws layout (floats): h | x | q | k | v | ctx | biasT ; ff aliases q..ctx (4*BSD_)
    float* h     = ws;
    float* x     = ws + 1 * BSD_;
    float* qbuf  = ws + 2 * BSD_;
    float* kbuf  = ws + 3 * BSD_;
    float* vbuf  = ws + 4 * BSD_;
    float* cbuf  = ws + 5 * BSD_;
    float* biasT = ws + 6 * BSD_;   // H*S*S == BSD_ floats exactly
    float* ff    = qbuf;            // 4*BSD_ region, dead by FFN time

    k_embed<<<BS_, 192, 0, stream>>>(ids, ew, h);
    k_posbias<<<(S_ * S_ + 255) / 256, 256, 0, stream>>>(rbw, biasT);

    for (int l = 0; l < L_; ++l) {
        k_rmsnorm<<<BS_, 256, 0, stream>>>(h, ln1 + (size_t)l * D_, x);
        k_gemm_qkv<<<dim3(BS_ / 128, D_ / 128, 3), 256, 0, stream>>>(
            x, qw + (size_t)l * D_ * D_, kw + (size_t)l * D_ * D_, vw + (size_t)l * D_ * D_,
            qbuf, kbuf, vbuf);
        k_attn<<<dim3(B_ * H_, S_ / 128), 128, 0, stream>>>(qbuf, kbuf, vbuf, biasT, mask, cbuf);
        k_gemm<false><<<dim3(BS_ / 128, D_ / 128), 256, 0, stream>>>(
            cbuf, ow + (size_t)l * D_ * D_, h, h, D_, D_);
        k_rmsnorm<<<BS_, 256, 0, stream>>>(h, ln2 + (size_t)l * D_, x);
        k_gemm<true><<<dim3(BS_ / 128, DFF_ / 128), 256, 0, stream>>>(
            x, wiw + (size_t)l * DFF_ * D_, nullptr, ff, DFF_, D_);
        k_gemm<false><<<dim3(BS_ / 128, D_ / 128), 256, 0, stream>>>(
            ff, wow + (size_t)l * D_ * DFF_, h, h, D_, DFF_);
    }
    k_rmsnorm<<<BS_, 256, 0, stream>>>(h, flnw, out);
}

// Round 2
// 3404.989 us; speedup vs baseline: 2.6875x; 2.6875x over previous
//
#include <hip/hip_runtime.h>
#include <hip/hip_bf16.h>
#include <math.h>

#define L_ 6
#define D_ 768
#define H_ 12
#define DK_ 64
#define DFF_ 3072
#define NB_ 32
#define MAXDIST_ 128
#define B_ 8
#define S_ 512
#define NEG_ (-1e9f)
#define BS_ (B_*S_)            // 4096 rows
#define BSD_ ((size_t)BS_*D_)  // 3,145,728 elements

typedef __bf16 bf16x8 __attribute__((ext_vector_type(8)));
typedef float f32x4 __attribute__((ext_vector_type(4)));
typedef unsigned short u16x8 __attribute__((ext_vector_type(8)));

__device__ __forceinline__ unsigned short f2bf(float f) {
    unsigned u = __float_as_uint(f);
    u += 0x7fff + ((u >> 16) & 1);          // round-to-nearest-even
    return (unsigned short)(u >> 16);
}
__device__ __forceinline__ float bf2f(unsigned short s) {
    return __uint_as_float(((unsigned)s) << 16);
}

#define GLDS(g, l) __builtin_amdgcn_global_load_lds( \
    (const __attribute__((address_space(1))) void*)(const void*)(g), \
    (__attribute__((address_space(3))) void*)(void*)(l), 16, 0, 0)

// ---------------- embedding gather ----------------
__global__ __launch_bounds__(192) void k_embed(const int* __restrict__ ids,
                                               const float* __restrict__ ew,
                                               float* __restrict__ h) {
    int row = blockIdx.x;
    int id = ids[row];
    const float4* src = (const float4*)(ew + (size_t)id * D_);
    float4* dst = (float4*)(h + (size_t)row * D_);
    dst[threadIdx.x] = src[threadIdx.x];
}

// ---------------- T5 RMSNorm (optionally bf16 output) ----------------
template<int OUTBF>
__global__ __launch_bounds__(256) void k_rmsnorm(const float* __restrict__ in,
                                                 const float* __restrict__ w,
                                                 void* __restrict__ outp) {
    int row = blockIdx.x;
    int tid = threadIdx.x;
    const float* x = in + (size_t)row * D_;
    float ss = 0.f;
    for (int i = tid; i < D_; i += 256) { float v = x[i]; ss += v * v; }
    #pragma unroll
    for (int off = 32; off; off >>= 1) ss += __shfl_down(ss, off, 64);
    __shared__ float sbuf[4];
    if ((tid & 63) == 0) sbuf[tid >> 6] = ss;
    __syncthreads();
    float tot = sbuf[0] + sbuf[1] + sbuf[2] + sbuf[3];
    float scale = rsqrtf(tot / (float)D_ + 1e-6f);
    if (OUTBF) {
        unsigned short* o = (unsigned short*)outp + (size_t)row * D_;
        for (int i = tid; i < D_; i += 256) o[i] = f2bf(w[i] * x[i] * scale);
    } else {
        float* o = (float*)outp + (size_t)row * D_;
        for (int i = tid; i < D_; i += 256) o[i] = w[i] * x[i] * scale;
    }
}

// ---------------- relative position bias (transposed, bf16: [h][key][q]) ----------------
__global__ __launch_bounds__(256) void k_posbias(const float* __restrict__ rbw,
                                                 unsigned short* __restrict__ biasT) {
    int idx = blockIdx.x * 256 + threadIdx.x;
    if (idx >= S_ * S_) return;
    int key = idx / S_, qi = idx - key * S_;
    int rel = key - qi;                          // memory - query
    const int nb = NB_ / 2;                      // 16
    int ret = rel > 0 ? nb : 0;
    int n = rel < 0 ? -rel : rel;
    const int max_exact = nb / 2;                // 8
    int val;
    if (n < max_exact) {
        val = n;
    } else {
        float lf = logf((float)n / (float)max_exact) /
                   logf((float)MAXDIST_ / (float)max_exact) * (float)(nb - max_exact);
        val = max_exact + (int)lf;
        if (val > nb - 1) val = nb - 1;
    }
    int bucket = ret + val;
    #pragma unroll
    for (int hh = 0; hh < H_; ++hh)
        biasT[((size_t)hh * S_ + key) * S_ + qi] = f2bf(rbw[bucket * H_ + hh]);
}

// ---------------- per-layer weight fp32 -> bf16 conversion ----------------
#define W1V8 73728    // 589824/8  (q,k,v,o per layer)
#define W2V8 294912   // 2359296/8 (wi, wo per layer)
__global__ __launch_bounds__(256) void k_wconv(const float* __restrict__ qw,
                                               const float* __restrict__ kw,
                                               const float* __restrict__ vw,
                                               const float* __restrict__ ow,
                                               const float* __restrict__ wiw,
                                               const float* __restrict__ wow,
                                               unsigned short* __restrict__ wb) {
    int gid = blockIdx.x * 256 + threadIdx.x;    // one v8 chunk each
    int i = gid;
    const float* src;
    if (i < W1V8)              src = qw;
    else if ((i -= W1V8) < W1V8) src = kw;
    else if ((i -= W1V8) < W1V8) src = vw;
    else if ((i -= W1V8) < W1V8) src = ow;
    else if ((i -= W1V8) < W2V8) src = wiw;
    else { i -= W2V8;            src = wow; }
    const float4* s4 = (const float4*)src + (size_t)i * 2;
    float4 a = s4[0], b = s4[1];
    u16x8 pk;
    pk[0] = f2bf(a.x); pk[1] = f2bf(a.y); pk[2] = f2bf(a.z); pk[3] = f2bf(a.w);
    pk[4] = f2bf(b.x); pk[5] = f2bf(b.y); pk[6] = f2bf(b.z); pk[7] = f2bf(b.w);
    *((u16x8*)(wb + (size_t)gid * 8)) = pk;
}

// ---------------- bf16 MFMA NT GEMM: C[m,n] = sum_k A[m,k]*B[n,k] ----------------
// 128x128 tile, BK=64, 4 waves (2x2 of 64x64), 16x16x32 MFMA, T2 XOR swizzle.
template<int RES, int RELU, int OUTBF>
__device__ __forceinline__ void gemm_bf_body(const unsigned short* __restrict__ A,
                                             const unsigned short* __restrict__ Bw,
                                             const float* __restrict__ res,
                                             void* __restrict__ C,
                                             int N, int K, int bm, int bn) {
    __shared__ __align__(16) unsigned short lsA[128 * 64];
    __shared__ __align__(16) unsigned short lsB[128 * 64];
    int t = threadIdx.x;
    int lane = t & 63, w = t >> 6;
    int wr = (w >> 1) * 64, wc = (w & 1) * 64;
    int l15 = lane & 15, l4 = lane >> 4;

    f32x4 acc[4][4] = {};

    const unsigned short* Abase = A + (size_t)(bm * 128) * K;
    const unsigned short* Bbase = Bw + (size_t)(bn * 128) * K;

    for (int k0 = 0; k0 < K; k0 += 64) {
        __syncthreads();                          // prev tile consumed
        #pragma unroll
        for (int c = 0; c < 4; ++c) {
            int off = c * 4096 + w * 1024 + lane * 16;   // byte offset in 8KB tile
            int row = off >> 7;
            int sc = (off & 127) ^ ((row & 7) << 4);     // pre-swizzled source col
            GLDS(Abase + (size_t)row * K + k0 + (sc >> 1), (char*)lsA + off);
        }
        #pragma unroll
        for (int c = 0; c < 4; ++c) {
            int off = c * 4096 + w * 1024 + lane * 16;
            int row = off >> 7;
            int sc = (off & 127) ^ ((row & 7) << 4);
            GLDS(Bbase + (size_t)row * K + k0 + (sc >> 1), (char*)lsB + off);
        }
        __syncthreads();                          // vmcnt(0) drained before barrier
        #pragma unroll
        for (int kk = 0; kk < 2; ++kk) {
            bf16x8 af[4], bfr[4];
            int kByte = kk * 64 + l4 * 16;
            #pragma unroll
            for (int i = 0; i < 4; ++i) {
                int r = wr + i * 16 + l15;
                af[i] = *(const bf16x8*)((const char*)lsA + r * 128 + (kByte ^ ((r & 7) << 4)));
            }
            #pragma unroll
            for (int j = 0; j < 4; ++j) {
                int r = wc + j * 16 + l15;
                bfr[j] = *(const bf16x8*)((const char*)lsB + r * 128 + (kByte ^ ((r & 7) << 4)));
            }
            #pragma unroll
            for (int i = 0; i < 4; ++i)
                #pragma unroll
                for (int j = 0; j < 4; ++j)
                    acc[i][j] = __builtin_amdgcn_mfma_f32_16x16x32_bf16(af[i], bfr[j], acc[i][j], 0, 0, 0);
        }
    }
    // epilogue: C/D layout col=lane&15, row=(lane>>4)*4+reg
    #pragma unroll
    for (int i = 0; i < 4; ++i) {
        #pragma unroll
        for (int r = 0; r < 4; ++r) {
            int row = bm * 128 + wr + i * 16 + l4 * 4 + r;
            #pragma unroll
            for (int j = 0; j < 4; ++j) {
                int col = bn * 128 + wc + j * 16 + l15;
                float v = acc[i][j][r];
                if (RES)  v += res[(size_t)row * N + col];
                if (RELU) v = fmaxf(v, 0.f);
                if (OUTBF) ((unsigned short*)C)[(size_t)row * N + col] = f2bf(v);
                else       ((float*)C)[(size_t)row * N + col] = v;
            }
        }
    }
}

template<int RES, int RELU, int OUTBF>
__global__ __launch_bounds__(256) void k_gemm_bf(const unsigned short* __restrict__ A,
                                                 const unsigned short* __restrict__ Bw,
                                                 const float* __restrict__ res,
                                                 void* __restrict__ C, int N, int K) {
    gemm_bf_body<RES, RELU, OUTBF>(A, Bw, res, C, N, K, blockIdx.x, blockIdx.y);
}

__global__ __launch_bounds__(256) void k_gemm_qkv_bf(const unsigned short* __restrict__ X,
                                                     const unsigned short* __restrict__ wq,
                                                     const unsigned short* __restrict__ wk,
                                                     const unsigned short* __restrict__ wv,
                                                     float* __restrict__ q,
                                                     float* __restrict__ k,
                                                     float* __restrict__ v) {
    const unsigned short* Bm = blockIdx.z == 0 ? wq : (blockIdx.z == 1 ? wk : wv);
    float* C = blockIdx.z == 0 ? q : (blockIdx.z == 1 ? k : v);
    gemm_bf_body<0, 0, 0>(X, Bm, nullptr, C, D_, D_, blockIdx.x, blockIdx.y);
}

// ---------------- attention: 1 thread = 1 query row, online softmax (fp32) ----------------
__global__ __launch_bounds__(128) void k_attn(const float* __restrict__ qb,
                                              const float* __restrict__ kb,
                                              const float* __restrict__ vb,
                                              const unsigned short* __restrict__ biasT,
                                              const float* __restrict__ mask,
                                              unsigned short* __restrict__ ctx) {
    __shared__ float Ks[64][64];
    __shared__ float Vs[64][64];
    int bh = blockIdx.x;
    int b = bh / H_, hh = bh - b * H_;
    int t = threadIdx.x;
    int qi = blockIdx.y * 128 + t;

    float qreg[64];
    {
        const float4* qp = (const float4*)(qb + ((size_t)(b * S_ + qi)) * D_ + hh * DK_);
        #pragma unroll
        for (int i = 0; i < 16; ++i) {
            float4 u = qp[i];
            qreg[4*i] = u.x; qreg[4*i+1] = u.y; qreg[4*i+2] = u.z; qreg[4*i+3] = u.w;
        }
    }
    float m = -3.0e38f, l = 0.f;
    float acc[64];
    #pragma unroll
    for (int d = 0; d < 64; ++d) acc[d] = 0.f;

    for (int kt = 0; kt < S_ / 64; ++kt) {
        __syncthreads();
        const float4* ksrc = (const float4*)(kb + ((size_t)(b * S_ + kt * 64)) * D_ + hh * DK_);
        const float4* vsrc = (const float4*)(vb + ((size_t)(b * S_ + kt * 64)) * D_ + hh * DK_);
        #pragma unroll
        for (int i = 0; i < 8; ++i) {
            int f = i * 128 + t;
            int row = f >> 4, c4 = f & 15;
            *(float4*)&Ks[row][c4 * 4] = ksrc[(size_t)row * (D_ / 4) + c4];
            *(float4*)&Vs[row][c4 * 4] = vsrc[(size_t)row * (D_ / 4) + c4];
        }
        __syncthreads();
        const unsigned short* bT = biasT + ((size_t)hh * S_ + kt * 64) * S_ + qi;
        const float* mp = mask + b * S_ + kt * 64;
        for (int j = 0; j < 64; ++j) {
            float s = 0.f;
            #pragma unroll
            for (int d = 0; d < 64; ++d) s = fmaf(qreg[d], Ks[j][d], s);
            s += bf2f(bT[(size_t)j * S_]);
            s += (1.f - mp[j]) * NEG_;
            if (s <= m) {
                float p = __expf(s - m);
                l += p;
                #pragma unroll
                for (int d = 0; d < 64; ++d) acc[d] = fmaf(p, Vs[j][d], acc[d]);
            } else {
                float sc = __expf(m - s);
                l = fmaf(l, sc, 1.f);
                #pragma unroll
                for (int d = 0; d < 64; ++d) acc[d] = fmaf(acc[d], sc, Vs[j][d]);
                m = s;
            }
        }
    }
    float inv = 1.f / l;
    unsigned short* op = ctx + ((size_t)(b * S_ + qi)) * D_ + hh * DK_;
    #pragma unroll
    for (int i = 0; i < 8; ++i) {
        u16x8 pk;
        #pragma unroll
        for (int j = 0; j < 8; ++j) pk[j] = f2bf(acc[i * 8 + j] * inv);
        *(u16x8*)(op + i * 8) = pk;
    }
}

// ---------------- launcher ----------------
extern "C" void kernel_launch(void* const* d_in, const int* in_sizes, int n_in,
                              void* d_out, int out_size, void* d_ws, size_t ws_size,
                              hipStream_t stream) {
    const int*   ids  = (const int*)d_in[0];
    const float* mask = (const float*)d_in[1];
    const float* ew   = (const float*)d_in[2];
    const float* ln1  = (const float*)d_in[3];
    const float* qw   = (const float*)d_in[4];
    const float* kw   = (const float*)d_in[5];
    const float* vw   = (const float*)d_in[6];
    const float* rbw  = (const float*)d_in[7];
    const float* ow   = (const float*)d_in[8];
    const float* ln2  = (const float*)d_in[9];
    const float* wiw  = (const float*)d_in[10];
    const float* wow  = (const float*)d_in[11];
    const float* flnw = (const float*)d_in[12];
    float* out = (float*)d_out;

    // ws layout (83.4 MB total; round-1 footprint 88.1 MB proved available)
    char* p = (char*)d_ws;
    float* h   = (float*)p;  p += BSD_ * 4;
    float* qf  = (float*)p;  p += BSD_ * 4;
    float* kf  = (float*)p;  p += BSD_ * 4;
    float* vf  = (float*)p;  p += BSD_ * 4;
    unsigned short* biasT = (unsigned short*)p;  p += (size_t)H_ * S_ * S_ * 2;
    unsigned short* xbf   = (unsigned short*)p;  p += BSD_ * 2;
    unsigned short* ctxb  = (unsigned short*)p;  p += BSD_ * 2;
    unsigned short* wbuf  = (unsigned short*)p;  p += (size_t)7077888 * 2;
    unsigned short* ff    = (unsigned short*)qf;   // aliases qf+kf (exactly 24 MB), dead by FFN

    const unsigned short* wq  = wbuf;
    const unsigned short* wk  = wbuf + 589824;
    const unsigned short* wv  = wbuf + 1179648;
    const unsigned short* wo  = wbuf + 1769472;
    const unsigned short* wwi = wbuf + 2359296;
    const unsigned short* wwo = wbuf + 4718592;

    k_embed<<<BS_, 192, 0, stream>>>(ids, ew, h);
    k_posbias<<<(S_ * S_ + 255) / 256, 256, 0, stream>>>(rbw, biasT);

    for (int l = 0; l < L_; ++l) {
        k_wconv<<<3456, 256, 0, stream>>>(qw + (size_t)l * 589824, kw + (size_t)l * 589824,
                                          vw + (size_t)l * 589824, ow + (size_t)l * 589824,
                                          wiw + (size_t)l * 2359296, wow + (size_t)l * 2359296,
                                          wbuf);
        k_rmsnorm<1><<<BS_, 256, 0, stream>>>(h, ln1 + (size_t)l * D_, xbf);
        k_gemm_qkv_bf<<<dim3(BS_ / 128, D_ / 128, 3), 256, 0, stream>>>(
            xbf, wq, wk, wv, qf, kf, vf);
        k_attn<<<dim3(B_ * H_, S_ / 128), 128, 0, stream>>>(qf, kf, vf, biasT, mask, ctxb);
        k_gemm_bf<1, 0, 0><<<dim3(BS_ / 128, D_ / 128), 256, 0, stream>>>(
            ctxb, wo, h, h, D_, D_);
        k_rmsnorm<1><<<BS_, 256, 0, stream>>>(h, ln2 + (size_t)l * D_, xbf);
        k_gemm_bf<0, 1, 1><<<dim3(BS_ / 128, DFF_ / 128), 256, 0, stream>>>(
            xbf, wwi, nullptr, ff, DFF_, D_);
        k_gemm_bf<1, 0, 0><<<dim3(BS_ / 128, D_ / 128), 256, 0, stream>>>(
            ff, wwo, h, h, D_, DFF_);
    }
    k_rmsnorm<0><<<BS_, 256, 0, stream>>>(h, flnw, out);
}

// Round 3
// 1093.676 us; speedup vs baseline: 8.3670x; 3.1133x over previous
//
#include <hip/hip_runtime.h>
#include <hip/hip_bf16.h>
#include <math.h>

#define L_ 6
#define D_ 768
#define H_ 12
#define DK_ 64
#define DFF_ 3072
#define NB_ 32
#define MAXDIST_ 128
#define B_ 8
#define S_ 512
#define NEG_ (-1e9f)
#define BS_ (B_*S_)            // 4096 rows
#define BSD_ ((size_t)BS_*D_)  // 3,145,728 elements

typedef __bf16 bf16x8 __attribute__((ext_vector_type(8)));
typedef float f32x4 __attribute__((ext_vector_type(4)));

__device__ __forceinline__ unsigned short f2bf(float f) {
    unsigned u = __float_as_uint(f);
    u += 0x7fff + ((u >> 16) & 1);          // RNE
    return (unsigned short)(u >> 16);
}
__device__ __forceinline__ float bf2f(unsigned short s) {
    return __uint_as_float(((unsigned)s) << 16);
}

#define GLDS(g, l) __builtin_amdgcn_global_load_lds( \
    (const __attribute__((address_space(1))) void*)(const void*)(g), \
    (__attribute__((address_space(3))) void*)(void*)(l), 16, 0, 0)

// ---------------- embedding gather ----------------
__global__ __launch_bounds__(192) void k_embed(const int* __restrict__ ids,
                                               const float* __restrict__ ew,
                                               float* __restrict__ h) {
    int row = blockIdx.x;
    int id = ids[row];
    const float4* src = (const float4*)(ew + (size_t)id * D_);
    float4* dst = (float4*)(h + (size_t)row * D_);
    dst[threadIdx.x] = src[threadIdx.x];
}

// ---------------- T5 RMSNorm ----------------
template<int OUTBF>
__global__ __launch_bounds__(256) void k_rmsnorm(const float* __restrict__ in,
                                                 const float* __restrict__ w,
                                                 void* __restrict__ outp) {
    int row = blockIdx.x;
    int tid = threadIdx.x;
    const float* x = in + (size_t)row * D_;
    float ss = 0.f;
    for (int i = tid; i < D_; i += 256) { float v = x[i]; ss += v * v; }
    #pragma unroll
    for (int off = 32; off; off >>= 1) ss += __shfl_down(ss, off, 64);
    __shared__ float sbuf[4];
    if ((tid & 63) == 0) sbuf[tid >> 6] = ss;
    __syncthreads();
    float tot = sbuf[0] + sbuf[1] + sbuf[2] + sbuf[3];
    float scale = rsqrtf(tot / (float)D_ + 1e-6f);
    if (OUTBF) {
        unsigned short* o = (unsigned short*)outp + (size_t)row * D_;
        for (int i = tid; i < D_; i += 256) o[i] = f2bf(w[i] * x[i] * scale);
    } else {
        float* o = (float*)outp + (size_t)row * D_;
        for (int i = tid; i < D_; i += 256) o[i] = w[i] * x[i] * scale;
    }
}

// ---------------- relative position bias, [h][q][key] bf16 ----------------
__global__ __launch_bounds__(256) void k_posbias(const float* __restrict__ rbw,
                                                 unsigned short* __restrict__ biasg) {
    int idx = blockIdx.x * 256 + threadIdx.x;
    if (idx >= S_ * S_) return;
    int q = idx / S_, key = idx - q * S_;
    int rel = key - q;                           // memory - query
    const int nb = NB_ / 2;                      // 16
    int ret = rel > 0 ? nb : 0;
    int n = rel < 0 ? -rel : rel;
    const int max_exact = nb / 2;                // 8
    int val;
    if (n < max_exact) {
        val = n;
    } else {
        float lf = logf((float)n / (float)max_exact) /
                   logf((float)MAXDIST_ / (float)max_exact) * (float)(nb - max_exact);
        val = max_exact + (int)lf;
        if (val > nb - 1) val = nb - 1;
    }
    int bucket = ret + val;
    #pragma unroll
    for (int hh = 0; hh < H_; ++hh)
        biasg[((size_t)hh * S_ + q) * S_ + key] = f2bf(rbw[bucket * H_ + hh]);
}

// ---------------- per-layer weight fp32 -> bf16 ----------------
#define W1V8 73728    // 589824/8
#define W2V8 294912   // 2359296/8
__global__ __launch_bounds__(256) void k_wconv(const float* __restrict__ qw,
                                               const float* __restrict__ kw,
                                               const float* __restrict__ vw,
                                               const float* __restrict__ ow,
                                               const float* __restrict__ wiw,
                                               const float* __restrict__ wow,
                                               unsigned short* __restrict__ wb) {
    int gid = blockIdx.x * 256 + threadIdx.x;
    int i = gid;
    const float* src;
    if (i < W1V8)                src = qw;
    else if ((i -= W1V8) < W1V8) src = kw;
    else if ((i -= W1V8) < W1V8) src = vw;
    else if ((i -= W1V8) < W1V8) src = ow;
    else if ((i -= W1V8) < W2V8) src = wiw;
    else { i -= W2V8;            src = wow; }
    const float4* s4 = (const float4*)src + (size_t)i * 2;
    float4 a = s4[0], b = s4[1];
    ushort4 lo, hi;
    lo.x = f2bf(a.x); lo.y = f2bf(a.y); lo.z = f2bf(a.z); lo.w = f2bf(a.w);
    hi.x = f2bf(b.x); hi.y = f2bf(b.y); hi.z = f2bf(b.z); hi.w = f2bf(b.w);
    ushort4* d = (ushort4*)(wb + (size_t)gid * 8);
    d[0] = lo; d[1] = hi;
}

// ---------------- shared MFMA GEMM core (128x128 tile, BK=64, NT) ----------------
__device__ __forceinline__ void gemm_core(const unsigned short* __restrict__ A,
                                          const unsigned short* __restrict__ Bw,
                                          int K, int bm, int bn,
                                          unsigned short* lsA, unsigned short* lsB,
                                          f32x4 acc[4][4]) {
    int t = threadIdx.x, lane = t & 63, w = t >> 6;
    int l15 = lane & 15, l4 = lane >> 4;
    int wr = (w >> 1) * 64, wc = (w & 1) * 64;
    const unsigned short* Abase = A + (size_t)(bm * 128) * K;
    const unsigned short* Bbase = Bw + (size_t)(bn * 128) * K;
    for (int k0 = 0; k0 < K; k0 += 64) {
        __syncthreads();
        #pragma unroll
        for (int c = 0; c < 4; ++c) {
            int off = c * 4096 + w * 1024 + lane * 16;
            int row = off >> 7;
            int sc = (off & 127) ^ ((row & 7) << 4);
            GLDS(Abase + (size_t)row * K + k0 + (sc >> 1), (char*)lsA + off);
        }
        #pragma unroll
        for (int c = 0; c < 4; ++c) {
            int off = c * 4096 + w * 1024 + lane * 16;
            int row = off >> 7;
            int sc = (off & 127) ^ ((row & 7) << 4);
            GLDS(Bbase + (size_t)row * K + k0 + (sc >> 1), (char*)lsB + off);
        }
        __syncthreads();
        #pragma unroll
        for (int kk = 0; kk < 2; ++kk) {
            bf16x8 af[4], bfr[4];
            int kByte = kk * 64 + l4 * 16;
            #pragma unroll
            for (int i = 0; i < 4; ++i) {
                int r = wr + i * 16 + l15;
                af[i] = *(const bf16x8*)((const char*)lsA + r * 128 + (kByte ^ ((r & 7) << 4)));
            }
            #pragma unroll
            for (int j = 0; j < 4; ++j) {
                int r = wc + j * 16 + l15;
                bfr[j] = *(const bf16x8*)((const char*)lsB + r * 128 + (kByte ^ ((r & 7) << 4)));
            }
            #pragma unroll
            for (int i = 0; i < 4; ++i)
                #pragma unroll
                for (int j = 0; j < 4; ++j)
                    acc[i][j] = __builtin_amdgcn_mfma_f32_16x16x32_bf16(af[i], bfr[j], acc[i][j], 0, 0, 0);
        }
    }
}

// standard epilogue GEMM (res fp32, optional relu, fp32/bf16 out)
template<int RES, int RELU, int OUTBF>
__global__ __launch_bounds__(256) void k_gemm_bf(const unsigned short* __restrict__ A,
                                                 const unsigned short* __restrict__ Bw,
                                                 const float* __restrict__ res,
                                                 void* __restrict__ C, int N, int K) {
    __shared__ __align__(16) unsigned short lsA[128 * 64];
    __shared__ __align__(16) unsigned short lsB[128 * 64];
    f32x4 acc[4][4] = {};
    int bm = blockIdx.x, bn = blockIdx.y;
    gemm_core(A, Bw, K, bm, bn, lsA, lsB, acc);
    int t = threadIdx.x, lane = t & 63, w = t >> 6;
    int l15 = lane & 15, l4 = lane >> 4;
    int wr = (w >> 1) * 64, wc = (w & 1) * 64;
    #pragma unroll
    for (int i = 0; i < 4; ++i) {
        #pragma unroll
        for (int r = 0; r < 4; ++r) {
            int row = bm * 128 + wr + i * 16 + l4 * 4 + r;
            #pragma unroll
            for (int j = 0; j < 4; ++j) {
                int col = bn * 128 + wc + j * 16 + l15;
                float v = acc[i][j][r];
                if (RES)  v += res[(size_t)row * N + col];
                if (RELU) v = fmaxf(v, 0.f);
                if (OUTBF) ((unsigned short*)C)[(size_t)row * N + col] = f2bf(v);
                else       ((float*)C)[(size_t)row * N + col] = v;
            }
        }
    }
}

// QKV: z=0 -> q (bf16 [B,S,768]), z=1 -> k (same), z=2 -> V^T bf16 [B*H, 64, 512]
__global__ __launch_bounds__(256) void k_gemm_qkv_bf(const unsigned short* __restrict__ X,
                                                     const unsigned short* __restrict__ wq,
                                                     const unsigned short* __restrict__ wk,
                                                     const unsigned short* __restrict__ wv,
                                                     unsigned short* __restrict__ qo,
                                                     unsigned short* __restrict__ ko,
                                                     unsigned short* __restrict__ vt) {
    __shared__ __align__(16) unsigned short lsA[128 * 64];
    __shared__ __align__(16) unsigned short lsB[128 * 64];
    f32x4 acc[4][4] = {};
    int z = blockIdx.z;
    const unsigned short* Bm = z == 0 ? wq : (z == 1 ? wk : wv);
    int bm = blockIdx.x, bn = blockIdx.y;
    gemm_core(X, Bm, D_, bm, bn, lsA, lsB, acc);
    int t = threadIdx.x, lane = t & 63, w = t >> 6;
    int l15 = lane & 15, l4 = lane >> 4;
    int wr = (w >> 1) * 64, wc = (w & 1) * 64;
    if (z < 2) {
        unsigned short* C = z == 0 ? qo : ko;
        #pragma unroll
        for (int i = 0; i < 4; ++i)
            #pragma unroll
            for (int r = 0; r < 4; ++r) {
                int row = bm * 128 + wr + i * 16 + l4 * 4 + r;
                #pragma unroll
                for (int j = 0; j < 4; ++j) {
                    int col = bn * 128 + wc + j * 16 + l15;
                    C[(size_t)row * D_ + col] = f2bf(acc[i][j][r]);
                }
            }
    } else {
        // V^T: vt[((b*H + h)*64 + dv)*512 + s], s = row%512, b = row/512
        #pragma unroll
        for (int i = 0; i < 4; ++i) {
            int row0 = bm * 128 + wr + i * 16 + l4 * 4;
            int b = row0 >> 9, s0 = row0 & 511;
            #pragma unroll
            for (int j = 0; j < 4; ++j) {
                int col = bn * 128 + wc + j * 16 + l15;
                int hh = col >> 6, dv = col & 63;
                ushort4 o4;
                o4.x = f2bf(acc[i][j][0]); o4.y = f2bf(acc[i][j][1]);
                o4.z = f2bf(acc[i][j][2]); o4.w = f2bf(acc[i][j][3]);
                *(ushort4*)(vt + (((size_t)b * H_ + hh) * 64 + dv) * S_ + s0) = o4;
            }
        }
    }
}

// ---------------- MFMA flash attention ----------------
// grid (8, 96): x = q-block of 64, y = b*H + h. 256 threads = 4 waves, wave owns 16 q.
// S^T = mfma(Kfrag, Qfrag): lane holds q = lane&15, keys = j*16 + (lane>>4)*4 + r.
// PV: ctx^T = mfma(VTfrag, Pfrag) with P via per-wave LDS round-trip.
__global__ __launch_bounds__(256) void k_attn_flash(const unsigned short* __restrict__ qb,
                                                    const unsigned short* __restrict__ kb,
                                                    const unsigned short* __restrict__ vtb,
                                                    const unsigned short* __restrict__ biasg,
                                                    const float* __restrict__ mask,
                                                    unsigned short* __restrict__ ctx) {
    __shared__ __align__(16) unsigned short Kt[64 * 64];
    __shared__ __align__(16) unsigned short Vt[64 * 64];
    __shared__ __align__(16) unsigned short Bt[64 * 64];
    __shared__ __align__(16) unsigned short Pt[4][16 * 64];

    int t = threadIdx.x, lane = t & 63, w = t >> 6;
    int l15 = lane & 15, l4 = lane >> 4;
    int bh = blockIdx.y;
    int b = bh / H_, hh = bh - b * H_;
    int qblk = blockIdx.x;
    int qloc = w * 16 + l15;          // q within 64-row block
    int qg = qblk * 64 + qloc;        // q within 512

    bf16x8 qf[2];
    {
        const unsigned short* qp = qb + ((size_t)(b * S_ + qg)) * D_ + hh * DK_;
        qf[0] = *(const bf16x8*)(qp + l4 * 8);
        qf[1] = *(const bf16x8*)(qp + 32 + l4 * 8);
    }
    float mrun = -1e30f, lsum = 0.f;
    f32x4 cacc[4] = {};

    for (int kt = 0; kt < S_ / 64; ++kt) {
        int kbase = kt * 64;
        __syncthreads();
        #pragma unroll
        for (int c = 0; c < 2; ++c) {
            int off = (w * 2 + c) * 1024 + lane * 16;      // byte offset in 8KB tile
            int row = off >> 7;
            int colb = (off & 127) ^ ((row & 7) << 4);     // pre-swizzled source col (bytes)
            GLDS(kb + ((size_t)(b * S_ + kbase + row)) * D_ + hh * DK_ + (colb >> 1),
                 (char*)Kt + off);
            GLDS(vtb + ((size_t)bh * 64 + row) * S_ + kbase + (colb >> 1),
                 (char*)Vt + off);
            GLDS(biasg + ((size_t)hh * S_ + qblk * 64 + row) * S_ + kbase + (colb >> 1),
                 (char*)Bt + off);
        }
        __syncthreads();

        // QK^T (swapped): sc[j] -> C[key_local][q]
        f32x4 sc[4] = {};
        #pragma unroll
        for (int kk = 0; kk < 2; ++kk) {
            int kByte = kk * 64 + l4 * 16;
            #pragma unroll
            for (int j = 0; j < 4; ++j) {
                int r = j * 16 + l15;
                bf16x8 kf = *(const bf16x8*)((const char*)Kt + r * 128 + (kByte ^ ((r & 7) << 4)));
                sc[j] = __builtin_amdgcn_mfma_f32_16x16x32_bf16(kf, qf[kk], sc[j], 0, 0, 0);
            }
        }
        // bias + mask, tile max
        float sv[4][4];
        float tmax = -1e30f;
        #pragma unroll
        for (int j = 0; j < 4; ++j) {
            int bro = qloc * 128 + ((j * 32 + l4 * 8) ^ ((qloc & 7) << 4));
            ushort4 b4 = *(const ushort4*)((const char*)Bt + bro);
            float4 m4 = *(const float4*)(mask + (size_t)b * S_ + kbase + j * 16 + l4 * 4);
            sv[j][0] = sc[j][0] + bf2f(b4.x) + (1.f - m4.x) * NEG_;
            sv[j][1] = sc[j][1] + bf2f(b4.y) + (1.f - m4.y) * NEG_;
            sv[j][2] = sc[j][2] + bf2f(b4.z) + (1.f - m4.z) * NEG_;
            sv[j][3] = sc[j][3] + bf2f(b4.w) + (1.f - m4.w) * NEG_;
            tmax = fmaxf(tmax, fmaxf(fmaxf(sv[j][0], sv[j][1]), fmaxf(sv[j][2], sv[j][3])));
        }
        tmax = fmaxf(tmax, __shfl_xor(tmax, 16, 64));
        tmax = fmaxf(tmax, __shfl_xor(tmax, 32, 64));
        float mnew = fmaxf(mrun, tmax);
        float scal = __expf(mrun - mnew);
        #pragma unroll
        for (int i = 0; i < 4; ++i) {
            cacc[i][0] *= scal; cacc[i][1] *= scal;
            cacc[i][2] *= scal; cacc[i][3] *= scal;
        }
        float psum = 0.f;
        unsigned pp[8];
        #pragma unroll
        for (int j = 0; j < 4; ++j) {
            float p0 = __expf(sv[j][0] - mnew), p1 = __expf(sv[j][1] - mnew);
            float p2 = __expf(sv[j][2] - mnew), p3 = __expf(sv[j][3] - mnew);
            psum += (p0 + p1) + (p2 + p3);
            pp[j * 2]     = (unsigned)f2bf(p0) | ((unsigned)f2bf(p1) << 16);
            pp[j * 2 + 1] = (unsigned)f2bf(p2) | ((unsigned)f2bf(p3) << 16);
        }
        lsum = lsum * scal + psum;
        mrun = mnew;
        // P round-trip (wave-local; same-wave LDS ops are ordered)
        unsigned short* P = Pt[w];
        #pragma unroll
        for (int j = 0; j < 4; ++j) {
            int base = l15 * 128 + ((j * 32 + l4 * 8) ^ ((l15 & 7) << 4));
            *(unsigned*)((char*)P + base) = pp[j * 2];
            *(unsigned*)((char*)P + base + 4) = pp[j * 2 + 1];
        }
        #pragma unroll
        for (int kk = 0; kk < 2; ++kk) {
            int kByte = kk * 64 + l4 * 16;
            bf16x8 pf = *(const bf16x8*)((const char*)P + l15 * 128 + (kByte ^ ((l15 & 7) << 4)));
            #pragma unroll
            for (int i = 0; i < 4; ++i) {
                int rr = i * 16 + l15;
                bf16x8 vf = *(const bf16x8*)((const char*)Vt + rr * 128 + (kByte ^ ((rr & 7) << 4)));
                cacc[i] = __builtin_amdgcn_mfma_f32_16x16x32_bf16(vf, pf, cacc[i], 0, 0, 0);
            }
        }
    }
    lsum += __shfl_xor(lsum, 16, 64);
    lsum += __shfl_xor(lsum, 32, 64);
    float inv = 1.f / lsum;
    unsigned short* cp = ctx + ((size_t)(b * S_ + qg)) * D_ + hh * DK_;
    #pragma unroll
    for (int i = 0; i < 4; ++i) {
        ushort4 o4;
        o4.x = f2bf(cacc[i][0] * inv); o4.y = f2bf(cacc[i][1] * inv);
        o4.z = f2bf(cacc[i][2] * inv); o4.w = f2bf(cacc[i][3] * inv);
        *(ushort4*)(cp + i * 16 + l4 * 4) = o4;
    }
}

// ---------------- launcher ----------------
extern "C" void kernel_launch(void* const* d_in, const int* in_sizes, int n_in,
                              void* d_out, int out_size, void* d_ws, size_t ws_size,
                              hipStream_t stream) {
    const int*   ids  = (const int*)d_in[0];
    const float* mask = (const float*)d_in[1];
    const float* ew   = (const float*)d_in[2];
    const float* ln1  = (const float*)d_in[3];
    const float* qw   = (const float*)d_in[4];
    const float* kw   = (const float*)d_in[5];
    const float* vw   = (const float*)d_in[6];
    const float* rbw  = (const float*)d_in[7];
    const float* ow   = (const float*)d_in[8];
    const float* ln2  = (const float*)d_in[9];
    const float* wiw  = (const float*)d_in[10];
    const float* wow  = (const float*)d_in[11];
    const float* flnw = (const float*)d_in[12];
    float* out = (float*)d_out;

    // ws layout (64.5 MB): h | biasg | wbuf | xbf(=ctxb) | qbB kbB vtb [+6.3MB] (ff aliases qbB..)
    char* p = (char*)d_ws;
    float* h = (float*)p;                        p += BSD_ * 4;
    unsigned short* biasg = (unsigned short*)p;  p += (size_t)H_ * S_ * S_ * 2;
    unsigned short* wbuf  = (unsigned short*)p;  p += (size_t)7077888 * 2;
    unsigned short* xbf   = (unsigned short*)p;  p += BSD_ * 2;
    unsigned short* ctxb  = xbf;                 // aliased: disjoint lifetimes
    unsigned short* qbB   = (unsigned short*)p;  p += BSD_ * 2;
    unsigned short* kbB   = (unsigned short*)p;  p += BSD_ * 2;
    unsigned short* vtb   = (unsigned short*)p;  p += BSD_ * 2;
    /* extra 6.3MB tail for ff */                p += BSD_ * 2;
    unsigned short* ff    = qbB;                 // 25.2MB spans qbB..tail, dead by FFN

    const unsigned short* wq  = wbuf;
    const unsigned short* wk  = wbuf + 589824;
    const unsigned short* wv  = wbuf + 1179648;
    const unsigned short* wo  = wbuf + 1769472;
    const unsigned short* wwi = wbuf + 2359296;
    const unsigned short* wwo = wbuf + 4718592;

    k_embed<<<BS_, 192, 0, stream>>>(ids, ew, h);
    k_posbias<<<(S_ * S_ + 255) / 256, 256, 0, stream>>>(rbw, biasg);

    for (int l = 0; l < L_; ++l) {
        k_wconv<<<3456, 256, 0, stream>>>(qw + (size_t)l * 589824, kw + (size_t)l * 589824,
                                          vw + (size_t)l * 589824, ow + (size_t)l * 589824,
                                          wiw + (size_t)l * 2359296, wow + (size_t)l * 2359296,
                                          wbuf);
        k_rmsnorm<1><<<BS_, 256, 0, stream>>>(h, ln1 + (size_t)l * D_, xbf);
        k_gemm_qkv_bf<<<dim3(BS_ / 128, D_ / 128, 3), 256, 0, stream>>>(
            xbf, wq, wk, wv, qbB, kbB, vtb);
        k_attn_flash<<<dim3(S_ / 64, B_ * H_), 256, 0, stream>>>(
            qbB, kbB, vtb, biasg, mask, ctxb);
        k_gemm_bf<1, 0, 0><<<dim3(BS_ / 128, D_ / 128), 256, 0, stream>>>(
            ctxb, wo, h, h, D_, D_);
        k_rmsnorm<1><<<BS_, 256, 0, stream>>>(h, ln2 + (size_t)l * D_, xbf);
        k_gemm_bf<0, 1, 1><<<dim3(BS_ / 128, DFF_ / 128), 256, 0, stream>>>(
            xbf, wwi, nullptr, ff, DFF_, D_);
        k_gemm_bf<1, 0, 0><<<dim3(BS_ / 128, D_ / 128), 256, 0, stream>>>(
            ff, wwo, h, h, D_, DFF_);
    }
    k_rmsnorm<0><<<BS_, 256, 0, stream>>>(h, flnw, out);
}

// Round 4
// 1077.742 us; speedup vs baseline: 8.4907x; 1.0148x over previous
//
#include <hip/hip_runtime.h>
#include <hip/hip_bf16.h>
#include <math.h>

#define L_ 6
#define D_ 768
#define H_ 12
#define DK_ 64
#define DFF_ 3072
#define NB_ 32
#define MAXDIST_ 128
#define B_ 8
#define S_ 512
#define NEG_ (-1e9f)
#define BS_ (B_*S_)            // 4096 rows
#define BSD_ ((size_t)BS_*D_)  // 3,145,728 elements

typedef __bf16 bf16x8 __attribute__((ext_vector_type(8)));
typedef float f32x4 __attribute__((ext_vector_type(4)));

__device__ __forceinline__ unsigned short f2bf(float f) {
    unsigned u = __float_as_uint(f);
    u += 0x7fff + ((u >> 16) & 1);          // RNE
    return (unsigned short)(u >> 16);
}
__device__ __forceinline__ float bf2f(unsigned short s) {
    return __uint_as_float(((unsigned)s) << 16);
}

#define GLDS(g, l) __builtin_amdgcn_global_load_lds( \
    (const __attribute__((address_space(1))) void*)(const void*)(g), \
    (__attribute__((address_space(3))) void*)(void*)(l), 16, 0, 0)

// ---------------- embedding gather ----------------
__global__ __launch_bounds__(192) void k_embed(const int* __restrict__ ids,
                                               const float* __restrict__ ew,
                                               float* __restrict__ h) {
    int row = blockIdx.x;
    int id = ids[row];
    const float4* src = (const float4*)(ew + (size_t)id * D_);
    float4* dst = (float4*)(h + (size_t)row * D_);
    dst[threadIdx.x] = src[threadIdx.x];
}

// ---------------- T5 RMSNorm ----------------
template<int OUTBF>
__global__ __launch_bounds__(256) void k_rmsnorm(const float* __restrict__ in,
                                                 const float* __restrict__ w,
                                                 void* __restrict__ outp) {
    int row = blockIdx.x;
    int tid = threadIdx.x;
    const float* x = in + (size_t)row * D_;
    float ss = 0.f;
    for (int i = tid; i < D_; i += 256) { float v = x[i]; ss += v * v; }
    #pragma unroll
    for (int off = 32; off; off >>= 1) ss += __shfl_down(ss, off, 64);
    __shared__ float sbuf[4];
    if ((tid & 63) == 0) sbuf[tid >> 6] = ss;
    __syncthreads();
    float tot = sbuf[0] + sbuf[1] + sbuf[2] + sbuf[3];
    float scale = rsqrtf(tot / (float)D_ + 1e-6f);
    if (OUTBF) {
        unsigned short* o = (unsigned short*)outp + (size_t)row * D_;
        for (int i = tid; i < D_; i += 256) o[i] = f2bf(w[i] * x[i] * scale);
    } else {
        float* o = (float*)outp + (size_t)row * D_;
        for (int i = tid; i < D_; i += 256) o[i] = w[i] * x[i] * scale;
    }
}

// ---------------- relative position bias, [h][q][key] bf16 ----------------
__global__ __launch_bounds__(256) void k_posbias(const float* __restrict__ rbw,
                                                 unsigned short* __restrict__ biasg) {
    int idx = blockIdx.x * 256 + threadIdx.x;
    if (idx >= S_ * S_) return;
    int q = idx / S_, key = idx - q * S_;
    int rel = key - q;                           // memory - query
    const int nb = NB_ / 2;                      // 16
    int ret = rel > 0 ? nb : 0;
    int n = rel < 0 ? -rel : rel;
    const int max_exact = nb / 2;                // 8
    int val;
    if (n < max_exact) {
        val = n;
    } else {
        float lf = logf((float)n / (float)max_exact) /
                   logf((float)MAXDIST_ / (float)max_exact) * (float)(nb - max_exact);
        val = max_exact + (int)lf;
        if (val > nb - 1) val = nb - 1;
    }
    int bucket = ret + val;
    #pragma unroll
    for (int hh = 0; hh < H_; ++hh)
        biasg[((size_t)hh * S_ + q) * S_ + key] = f2bf(rbw[bucket * H_ + hh]);
}

// ---------------- per-layer weight fp32 -> bf16 ----------------
#define W1V8 73728    // 589824/8
#define W2V8 294912   // 2359296/8
__global__ __launch_bounds__(256) void k_wconv(const float* __restrict__ qw,
                                               const float* __restrict__ kw,
                                               const float* __restrict__ vw,
                                               const float* __restrict__ ow,
                                               const float* __restrict__ wiw,
                                               const float* __restrict__ wow,
                                               unsigned short* __restrict__ wb) {
    int gid = blockIdx.x * 256 + threadIdx.x;
    int i = gid;
    const float* src;
    if (i < W1V8)                src = qw;
    else if ((i -= W1V8) < W1V8) src = kw;
    else if ((i -= W1V8) < W1V8) src = vw;
    else if ((i -= W1V8) < W1V8) src = ow;
    else if ((i -= W1V8) < W2V8) src = wiw;
    else { i -= W2V8;            src = wow; }
    const float4* s4 = (const float4*)src + (size_t)i * 2;
    float4 a = s4[0], b = s4[1];
    ushort4 lo, hi;
    lo.x = f2bf(a.x); lo.y = f2bf(a.y); lo.z = f2bf(a.z); lo.w = f2bf(a.w);
    hi.x = f2bf(b.x); hi.y = f2bf(b.y); hi.z = f2bf(b.z); hi.w = f2bf(b.w);
    ushort4* d = (ushort4*)(wb + (size_t)gid * 8);
    d[0] = lo; d[1] = hi;
}

// ---------------- double-buffered MFMA GEMM core (128x128 tile, BK=64, NT) ----------------
// T3/T4 minimum 2-phase: stage(next) -> vmcnt(8) -> barrier -> compute(cur) -> barrier.
__device__ __forceinline__ void stage_tile(const unsigned short* __restrict__ Abase,
                                           const unsigned short* __restrict__ Bbase,
                                           int k0, int K, int buf,
                                           unsigned short* lsA, unsigned short* lsB,
                                           int w, int lane) {
    #pragma unroll
    for (int c = 0; c < 4; ++c) {
        int off = c * 4096 + w * 1024 + lane * 16;     // byte offset in 8KB half-tile
        int row = off >> 7;
        int sc = (off & 127) ^ ((row & 7) << 4);       // pre-swizzled source col (bytes)
        GLDS(Abase + (size_t)row * K + k0 + (sc >> 1), (char*)lsA + buf * 16384 + off);
    }
    #pragma unroll
    for (int c = 0; c < 4; ++c) {
        int off = c * 4096 + w * 1024 + lane * 16;
        int row = off >> 7;
        int sc = (off & 127) ^ ((row & 7) << 4);
        GLDS(Bbase + (size_t)row * K + k0 + (sc >> 1), (char*)lsB + buf * 16384 + off);
    }
}

__device__ __forceinline__ void gemm_compute64(const char* cA, const char* cB,
                                               f32x4 acc[4][4], int l15, int l4,
                                               int wr, int wc) {
    #pragma unroll
    for (int kk = 0; kk < 2; ++kk) {
        bf16x8 af[4], bfr[4];
        int kByte = kk * 64 + l4 * 16;
        #pragma unroll
        for (int i = 0; i < 4; ++i) {
            int r = wr + i * 16 + l15;
            af[i] = *(const bf16x8*)(cA + r * 128 + (kByte ^ ((r & 7) << 4)));
        }
        #pragma unroll
        for (int j = 0; j < 4; ++j) {
            int r = wc + j * 16 + l15;
            bfr[j] = *(const bf16x8*)(cB + r * 128 + (kByte ^ ((r & 7) << 4)));
        }
        #pragma unroll
        for (int i = 0; i < 4; ++i)
            #pragma unroll
            for (int j = 0; j < 4; ++j)
                acc[i][j] = __builtin_amdgcn_mfma_f32_16x16x32_bf16(af[i], bfr[j], acc[i][j], 0, 0, 0);
    }
}

__device__ __forceinline__ void gemm_core(const unsigned short* __restrict__ A,
                                          const unsigned short* __restrict__ Bw,
                                          int K, int bm, int bn,
                                          unsigned short* lsA, unsigned short* lsB,  // each 2x8KB
                                          f32x4 acc[4][4]) {
    int t = threadIdx.x, lane = t & 63, w = t >> 6;
    int l15 = lane & 15, l4 = lane >> 4;
    int wr = (w >> 1) * 64, wc = (w & 1) * 64;
    const unsigned short* Abase = A + (size_t)(bm * 128) * K;
    const unsigned short* Bbase = Bw + (size_t)(bn * 128) * K;
    int nt = K >> 6;

    stage_tile(Abase, Bbase, 0, K, 0, lsA, lsB, w, lane);     // prologue: tile 0 -> buf 0
    for (int tq = 0; tq < nt - 1; ++tq) {
        int cur = tq & 1;
        stage_tile(Abase, Bbase, (tq + 1) << 6, K, cur ^ 1, lsA, lsB, w, lane);
        asm volatile("s_waitcnt vmcnt(8)" ::: "memory");      // cur's 8 loads done; next 8 in flight
        __builtin_amdgcn_s_barrier();
        gemm_compute64((const char*)lsA + cur * 16384, (const char*)lsB + cur * 16384,
                       acc, l15, l4, wr, wc);
        asm volatile("s_waitcnt lgkmcnt(0)" ::: "memory");    // reads of cur complete
        __builtin_amdgcn_s_barrier();                          // before cur is restaged next iter
    }
    int cur = (nt - 1) & 1;
    asm volatile("s_waitcnt vmcnt(0)" ::: "memory");
    __builtin_amdgcn_s_barrier();
    gemm_compute64((const char*)lsA + cur * 16384, (const char*)lsB + cur * 16384,
                   acc, l15, l4, wr, wc);
}

// standard epilogue GEMM (res fp32, optional relu, fp32/bf16 out)
template<int RES, int RELU, int OUTBF>
__global__ __launch_bounds__(256) void k_gemm_bf(const unsigned short* __restrict__ A,
                                                 const unsigned short* __restrict__ Bw,
                                                 const float* __restrict__ res,
                                                 void* __restrict__ C, int N, int K) {
    __shared__ __align__(16) unsigned short lsA[2 * 128 * 64];
    __shared__ __align__(16) unsigned short lsB[2 * 128 * 64];
    f32x4 acc[4][4] = {};
    int bm = blockIdx.x, bn = blockIdx.y;
    gemm_core(A, Bw, K, bm, bn, lsA, lsB, acc);
    int t = threadIdx.x, lane = t & 63, w = t >> 6;
    int l15 = lane & 15, l4 = lane >> 4;
    int wr = (w >> 1) * 64, wc = (w & 1) * 64;
    #pragma unroll
    for (int i = 0; i < 4; ++i) {
        #pragma unroll
        for (int r = 0; r < 4; ++r) {
            int row = bm * 128 + wr + i * 16 + l4 * 4 + r;
            #pragma unroll
            for (int j = 0; j < 4; ++j) {
                int col = bn * 128 + wc + j * 16 + l15;
                float v = acc[i][j][r];
                if (RES)  v += res[(size_t)row * N + col];
                if (RELU) v = fmaxf(v, 0.f);
                if (OUTBF) ((unsigned short*)C)[(size_t)row * N + col] = f2bf(v);
                else       ((float*)C)[(size_t)row * N + col] = v;
            }
        }
    }
}

// QKV: z=0 -> q (bf16 [B,S,768]), z=1 -> k (same), z=2 -> V^T bf16 [B*H, 64, 512]
__global__ __launch_bounds__(256) void k_gemm_qkv_bf(const unsigned short* __restrict__ X,
                                                     const unsigned short* __restrict__ wq,
                                                     const unsigned short* __restrict__ wk,
                                                     const unsigned short* __restrict__ wv,
                                                     unsigned short* __restrict__ qo,
                                                     unsigned short* __restrict__ ko,
                                                     unsigned short* __restrict__ vt) {
    __shared__ __align__(16) unsigned short lsA[2 * 128 * 64];
    __shared__ __align__(16) unsigned short lsB[2 * 128 * 64];
    f32x4 acc[4][4] = {};
    int z = blockIdx.z;
    const unsigned short* Bm = z == 0 ? wq : (z == 1 ? wk : wv);
    int bm = blockIdx.x, bn = blockIdx.y;
    gemm_core(X, Bm, D_, bm, bn, lsA, lsB, acc);
    int t = threadIdx.x, lane = t & 63, w = t >> 6;
    int l15 = lane & 15, l4 = lane >> 4;
    int wr = (w >> 1) * 64, wc = (w & 1) * 64;
    if (z < 2) {
        unsigned short* C = z == 0 ? qo : ko;
        #pragma unroll
        for (int i = 0; i < 4; ++i)
            #pragma unroll
            for (int r = 0; r < 4; ++r) {
                int row = bm * 128 + wr + i * 16 + l4 * 4 + r;
                #pragma unroll
                for (int j = 0; j < 4; ++j) {
                    int col = bn * 128 + wc + j * 16 + l15;
                    C[(size_t)row * D_ + col] = f2bf(acc[i][j][r]);
                }
            }
    } else {
        // V^T: vt[((b*H + h)*64 + dv)*512 + s], s = row%512, b = row/512
        #pragma unroll
        for (int i = 0; i < 4; ++i) {
            int row0 = bm * 128 + wr + i * 16 + l4 * 4;
            int b = row0 >> 9, s0 = row0 & 511;
            #pragma unroll
            for (int j = 0; j < 4; ++j) {
                int col = bn * 128 + wc + j * 16 + l15;
                int hh = col >> 6, dv = col & 63;
                ushort4 o4;
                o4.x = f2bf(acc[i][j][0]); o4.y = f2bf(acc[i][j][1]);
                o4.z = f2bf(acc[i][j][2]); o4.w = f2bf(acc[i][j][3]);
                *(ushort4*)(vt + (((size_t)b * H_ + hh) * 64 + dv) * S_ + s0) = o4;
            }
        }
    }
}

// ---------------- MFMA flash attention ----------------
__global__ __launch_bounds__(256) void k_attn_flash(const unsigned short* __restrict__ qb,
                                                    const unsigned short* __restrict__ kb,
                                                    const unsigned short* __restrict__ vtb,
                                                    const unsigned short* __restrict__ biasg,
                                                    const float* __restrict__ mask,
                                                    unsigned short* __restrict__ ctx) {
    __shared__ __align__(16) unsigned short Kt[64 * 64];
    __shared__ __align__(16) unsigned short Vt[64 * 64];
    __shared__ __align__(16) unsigned short Bt[64 * 64];
    __shared__ __align__(16) unsigned short Pt[4][16 * 64];

    int t = threadIdx.x, lane = t & 63, w = t >> 6;
    int l15 = lane & 15, l4 = lane >> 4;
    int bh = blockIdx.y;
    int b = bh / H_, hh = bh - b * H_;
    int qblk = blockIdx.x;
    int qloc = w * 16 + l15;
    int qg = qblk * 64 + qloc;

    bf16x8 qf[2];
    {
        const unsigned short* qp = qb + ((size_t)(b * S_ + qg)) * D_ + hh * DK_;
        qf[0] = *(const bf16x8*)(qp + l4 * 8);
        qf[1] = *(const bf16x8*)(qp + 32 + l4 * 8);
    }
    float mrun = -1e30f, lsum = 0.f;
    f32x4 cacc[4] = {};

    for (int kt = 0; kt < S_ / 64; ++kt) {
        int kbase = kt * 64;
        __syncthreads();
        #pragma unroll
        for (int c = 0; c < 2; ++c) {
            int off = (w * 2 + c) * 1024 + lane * 16;
            int row = off >> 7;
            int colb = (off & 127) ^ ((row & 7) << 4);
            GLDS(kb + ((size_t)(b * S_ + kbase + row)) * D_ + hh * DK_ + (colb >> 1),
                 (char*)Kt + off);
            GLDS(vtb + ((size_t)bh * 64 + row) * S_ + kbase + (colb >> 1),
                 (char*)Vt + off);
            GLDS(biasg + ((size_t)hh * S_ + qblk * 64 + row) * S_ + kbase + (colb >> 1),
                 (char*)Bt + off);
        }
        __syncthreads();

        f32x4 sc[4] = {};
        #pragma unroll
        for (int kk = 0; kk < 2; ++kk) {
            int kByte = kk * 64 + l4 * 16;
            #pragma unroll
            for (int j = 0; j < 4; ++j) {
                int r = j * 16 + l15;
                bf16x8 kf = *(const bf16x8*)((const char*)Kt + r * 128 + (kByte ^ ((r & 7) << 4)));
                sc[j] = __builtin_amdgcn_mfma_f32_16x16x32_bf16(kf, qf[kk], sc[j], 0, 0, 0);
            }
        }
        float sv[4][4];
        float tmax = -1e30f;
        #pragma unroll
        for (int j = 0; j < 4; ++j) {
            int bro = qloc * 128 + ((j * 32 + l4 * 8) ^ ((qloc & 7) << 4));
            ushort4 b4 = *(const ushort4*)((const char*)Bt + bro);
            float4 m4 = *(const float4*)(mask + (size_t)b * S_ + kbase + j * 16 + l4 * 4);
            sv[j][0] = sc[j][0] + bf2f(b4.x) + (1.f - m4.x) * NEG_;
            sv[j][1] = sc[j][1] + bf2f(b4.y) + (1.f - m4.y) * NEG_;
            sv[j][2] = sc[j][2] + bf2f(b4.z) + (1.f - m4.z) * NEG_;
            sv[j][3] = sc[j][3] + bf2f(b4.w) + (1.f - m4.w) * NEG_;
            tmax = fmaxf(tmax, fmaxf(fmaxf(sv[j][0], sv[j][1]), fmaxf(sv[j][2], sv[j][3])));
        }
        tmax = fmaxf(tmax, __shfl_xor(tmax, 16, 64));
        tmax = fmaxf(tmax, __shfl_xor(tmax, 32, 64));
        float mnew = fmaxf(mrun, tmax);
        float scal = __expf(mrun - mnew);
        #pragma unroll
        for (int i = 0; i < 4; ++i) {
            cacc[i][0] *= scal; cacc[i][1] *= scal;
            cacc[i][2] *= scal; cacc[i][3] *= scal;
        }
        float psum = 0.f;
        unsigned pp[8];
        #pragma unroll
        for (int j = 0; j < 4; ++j) {
            float p0 = __expf(sv[j][0] - mnew), p1 = __expf(sv[j][1] - mnew);
            float p2 = __expf(sv[j][2] - mnew), p3 = __expf(sv[j][3] - mnew);
            psum += (p0 + p1) + (p2 + p3);
            pp[j * 2]     = (unsigned)f2bf(p0) | ((unsigned)f2bf(p1) << 16);
            pp[j * 2 + 1] = (unsigned)f2bf(p2) | ((unsigned)f2bf(p3) << 16);
        }
        lsum = lsum * scal + psum;
        mrun = mnew;
        unsigned short* P = Pt[w];
        #pragma unroll
        for (int j = 0; j < 4; ++j) {
            int base = l15 * 128 + ((j * 32 + l4 * 8) ^ ((l15 & 7) << 4));
            *(unsigned*)((char*)P + base) = pp[j * 2];
            *(unsigned*)((char*)P + base + 4) = pp[j * 2 + 1];
        }
        #pragma unroll
        for (int kk = 0; kk < 2; ++kk) {
            int kByte = kk * 64 + l4 * 16;
            bf16x8 pf = *(const bf16x8*)((const char*)P + l15 * 128 + (kByte ^ ((l15 & 7) << 4)));
            #pragma unroll
            for (int i = 0; i < 4; ++i) {
                int rr = i * 16 + l15;
                bf16x8 vf = *(const bf16x8*)((const char*)Vt + rr * 128 + (kByte ^ ((rr & 7) << 4)));
                cacc[i] = __builtin_amdgcn_mfma_f32_16x16x32_bf16(vf, pf, cacc[i], 0, 0, 0);
            }
        }
    }
    lsum += __shfl_xor(lsum, 16, 64);
    lsum += __shfl_xor(lsum, 32, 64);
    float inv = 1.f / lsum;
    unsigned short* cp = ctx + ((size_t)(b * S_ + qg)) * D_ + hh * DK_;
    #pragma unroll
    for (int i = 0; i < 4; ++i) {
        ushort4 o4;
        o4.x = f2bf(cacc[i][0] * inv); o4.y = f2bf(cacc[i][1] * inv);
        o4.z = f2bf(cacc[i][2] * inv); o4.w = f2bf(cacc[i][3] * inv);
        *(ushort4*)(cp + i * 16 + l4 * 4) = o4;
    }
}

// ---------------- launcher ----------------
extern "C" void kernel_launch(void* const* d_in, const int* in_sizes, int n_in,
                              void* d_out, int out_size, void* d_ws, size_t ws_size,
                              hipStream_t stream) {
    const int*   ids  = (const int*)d_in[0];
    const float* mask = (const float*)d_in[1];
    const float* ew   = (const float*)d_in[2];
    const float* ln1  = (const float*)d_in[3];
    const float* qw   = (const float*)d_in[4];
    const float* kw   = (const float*)d_in[5];
    const float* vw   = (const float*)d_in[6];
    const float* rbw  = (const float*)d_in[7];
    const float* ow   = (const float*)d_in[8];
    const float* ln2  = (const float*)d_in[9];
    const float* wiw  = (const float*)d_in[10];
    const float* wow  = (const float*)d_in[11];
    const float* flnw = (const float*)d_in[12];
    float* out = (float*)d_out;

    // ws layout (64.5 MB): h | biasg | wbuf | xbf(=ctxb) | qbB kbB vtb [+6.3MB] (ff aliases qbB..)
    char* p = (char*)d_ws;
    float* h = (float*)p;                        p += BSD_ * 4;
    unsigned short* biasg = (unsigned short*)p;  p += (size_t)H_ * S_ * S_ * 2;
    unsigned short* wbuf  = (unsigned short*)p;  p += (size_t)7077888 * 2;
    unsigned short* xbf   = (unsigned short*)p;  p += BSD_ * 2;
    unsigned short* ctxb  = xbf;                 // aliased: disjoint lifetimes
    unsigned short* qbB   = (unsigned short*)p;  p += BSD_ * 2;
    unsigned short* kbB   = (unsigned short*)p;  p += BSD_ * 2;
    unsigned short* vtb   = (unsigned short*)p;  p += BSD_ * 2;
    /* extra 6.3MB tail for ff */                p += BSD_ * 2;
    unsigned short* ff    = qbB;                 // 25.2MB spans qbB..tail, dead by FFN

    const unsigned short* wq  = wbuf;
    const unsigned short* wk  = wbuf + 589824;
    const unsigned short* wv  = wbuf + 1179648;
    const unsigned short* wo  = wbuf + 1769472;
    const unsigned short* wwi = wbuf + 2359296;
    const unsigned short* wwo = wbuf + 4718592;

    k_embed<<<BS_, 192, 0, stream>>>(ids, ew, h);
    k_posbias<<<(S_ * S_ + 255) / 256, 256, 0, stream>>>(rbw, biasg);

    for (int l = 0; l < L_; ++l) {
        k_wconv<<<3456, 256, 0, stream>>>(qw + (size_t)l * 589824, kw + (size_t)l * 589824,
                                          vw + (size_t)l * 589824, ow + (size_t)l * 589824,
                                          wiw + (size_t)l * 2359296, wow + (size_t)l * 2359296,
                                          wbuf);
        k_rmsnorm<1><<<BS_, 256, 0, stream>>>(h, ln1 + (size_t)l * D_, xbf);
        k_gemm_qkv_bf<<<dim3(BS_ / 128, D_ / 128, 3), 256, 0, stream>>>(
            xbf, wq, wk, wv, qbB, kbB, vtb);
        k_attn_flash<<<dim3(S_ / 64, B_ * H_), 256, 0, stream>>>(
            qbB, kbB, vtb, biasg, mask, ctxb);
        k_gemm_bf<1, 0, 0><<<dim3(BS_ / 128, D_ / 128), 256, 0, stream>>>(
            ctxb, wo, h, h, D_, D_);
        k_rmsnorm<1><<<BS_, 256, 0, stream>>>(h, ln2 + (size_t)l * D_, xbf);
        k_gemm_bf<0, 1, 1><<<dim3(BS_ / 128, DFF_ / 128), 256, 0, stream>>>(
            xbf, wwi, nullptr, ff, DFF_, D_);
        k_gemm_bf<1, 0, 0><<<dim3(BS_ / 128, D_ / 128), 256, 0, stream>>>(
            ff, wwo, h, h, D_, DFF_);
    }
    k_rmsnorm<0><<<BS_, 256, 0, stream>>>(h, flnw, out);
}

// Round 5
// 935.762 us; speedup vs baseline: 9.7789x; 1.1517x over previous
//
#include <hip/hip_runtime.h>
#include <hip/hip_bf16.h>
#include <math.h>

#define L_ 6
#define D_ 768
#define H_ 12
#define DK_ 64
#define DFF_ 3072
#define NB_ 32
#define MAXDIST_ 128
#define B_ 8
#define S_ 512
#define NEG_ (-1e9f)
#define BS_ (B_*S_)            // 4096 rows
#define BSD_ ((size_t)BS_*D_)  // 3,145,728 elements

typedef __bf16 bf16x8 __attribute__((ext_vector_type(8)));
typedef float f32x4 __attribute__((ext_vector_type(4)));

__device__ __forceinline__ unsigned short f2bf(float f) {
    unsigned u = __float_as_uint(f);
    u += 0x7fff + ((u >> 16) & 1);          // RNE
    return (unsigned short)(u >> 16);
}
__device__ __forceinline__ float bf2f(unsigned short s) {
    return __uint_as_float(((unsigned)s) << 16);
}

#define GLDS(g, l) __builtin_amdgcn_global_load_lds( \
    (const __attribute__((address_space(1))) void*)(const void*)(g), \
    (__attribute__((address_space(3))) void*)(void*)(l), 16, 0, 0)

// ---------------- embedding gather ----------------
__global__ __launch_bounds__(192) void k_embed(const int* __restrict__ ids,
                                               const float* __restrict__ ew,
                                               float* __restrict__ h) {
    int row = blockIdx.x;
    int id = ids[row];
    const float4* src = (const float4*)(ew + (size_t)id * D_);
    float4* dst = (float4*)(h + (size_t)row * D_);
    dst[threadIdx.x] = src[threadIdx.x];
}

// ---------------- T5 RMSNorm ----------------
template<int OUTBF>
__global__ __launch_bounds__(256) void k_rmsnorm(const float* __restrict__ in,
                                                 const float* __restrict__ w,
                                                 void* __restrict__ outp) {
    int row = blockIdx.x;
    int tid = threadIdx.x;
    const float* x = in + (size_t)row * D_;
    float ss = 0.f;
    for (int i = tid; i < D_; i += 256) { float v = x[i]; ss += v * v; }
    #pragma unroll
    for (int off = 32; off; off >>= 1) ss += __shfl_down(ss, off, 64);
    __shared__ float sbuf[4];
    if ((tid & 63) == 0) sbuf[tid >> 6] = ss;
    __syncthreads();
    float tot = sbuf[0] + sbuf[1] + sbuf[2] + sbuf[3];
    float scale = rsqrtf(tot / (float)D_ + 1e-6f);
    if (OUTBF) {
        unsigned short* o = (unsigned short*)outp + (size_t)row * D_;
        for (int i = tid; i < D_; i += 256) o[i] = f2bf(w[i] * x[i] * scale);
    } else {
        float* o = (float*)outp + (size_t)row * D_;
        for (int i = tid; i < D_; i += 256) o[i] = w[i] * x[i] * scale;
    }
}

// ---------------- relative position bias, [h][q][key] bf16 ----------------
__global__ __launch_bounds__(256) void k_posbias(const float* __restrict__ rbw,
                                                 unsigned short* __restrict__ biasg) {
    int idx = blockIdx.x * 256 + threadIdx.x;
    if (idx >= S_ * S_) return;
    int q = idx / S_, key = idx - q * S_;
    int rel = key - q;                           // memory - query
    const int nb = NB_ / 2;                      // 16
    int ret = rel > 0 ? nb : 0;
    int n = rel < 0 ? -rel : rel;
    const int max_exact = nb / 2;                // 8
    int val;
    if (n < max_exact) {
        val = n;
    } else {
        float lf = logf((float)n / (float)max_exact) /
                   logf((float)MAXDIST_ / (float)max_exact) * (float)(nb - max_exact);
        val = max_exact + (int)lf;
        if (val > nb - 1) val = nb - 1;
    }
    int bucket = ret + val;
    #pragma unroll
    for (int hh = 0; hh < H_; ++hh)
        biasg[((size_t)hh * S_ + q) * S_ + key] = f2bf(rbw[bucket * H_ + hh]);
}

// ---------------- per-layer weight fp32 -> bf16 ----------------
#define W1V8 73728    // 589824/8
#define W2V8 294912   // 2359296/8
__global__ __launch_bounds__(256) void k_wconv(const float* __restrict__ qw,
                                               const float* __restrict__ kw,
                                               const float* __restrict__ vw,
                                               const float* __restrict__ ow,
                                               const float* __restrict__ wiw,
                                               const float* __restrict__ wow,
                                               unsigned short* __restrict__ wb) {
    int gid = blockIdx.x * 256 + threadIdx.x;
    int i = gid;
    const float* src;
    if (i < W1V8)                src = qw;
    else if ((i -= W1V8) < W1V8) src = kw;
    else if ((i -= W1V8) < W1V8) src = vw;
    else if ((i -= W1V8) < W1V8) src = ow;
    else if ((i -= W1V8) < W2V8) src = wiw;
    else { i -= W2V8;            src = wow; }
    const float4* s4 = (const float4*)src + (size_t)i * 2;
    float4 a = s4[0], b = s4[1];
    ushort4 lo, hi;
    lo.x = f2bf(a.x); lo.y = f2bf(a.y); lo.z = f2bf(a.z); lo.w = f2bf(a.w);
    hi.x = f2bf(b.x); hi.y = f2bf(b.y); hi.z = f2bf(b.z); hi.w = f2bf(b.w);
    ushort4* d = (ushort4*)(wb + (size_t)gid * 8);
    d[0] = lo; d[1] = hi;
}

// ---------------- templated double-buffered MFMA GEMM core (BMxBN, BK=64, NT) ----------------
// 4 waves as 2x2; wave sub-tile (BM/2)x(BN/2). 2-phase: stage(next)->vmcnt(n)->bar->mfma->bar.
template<int BM, int BN>
__device__ __forceinline__ void stage_tile_t(const unsigned short* __restrict__ Abase,
                                             const unsigned short* __restrict__ Bbase,
                                             int k0, int K, int buf,
                                             unsigned short* lsA, unsigned short* lsB,
                                             int w, int lane) {
    constexpr int CA = BM / 32, CB = BN / 32;
    #pragma unroll
    for (int c = 0; c < CA; ++c) {
        int off = c * 4096 + w * 1024 + lane * 16;     // byte offset in BM*128 half-tile
        int row = off >> 7;
        int sc = (off & 127) ^ ((row & 7) << 4);       // pre-swizzled source col (bytes)
        GLDS(Abase + (size_t)row * K + k0 + (sc >> 1), (char*)lsA + buf * (BM * 128) + off);
    }
    #pragma unroll
    for (int c = 0; c < CB; ++c) {
        int off = c * 4096 + w * 1024 + lane * 16;
        int row = off >> 7;
        int sc = (off & 127) ^ ((row & 7) << 4);
        GLDS(Bbase + (size_t)row * K + k0 + (sc >> 1), (char*)lsB + buf * (BN * 128) + off);
    }
}

template<int BM, int BN>
__device__ __forceinline__ void gemm_compute_t(const char* cA, const char* cB,
                                               f32x4 acc[BM / 32][BN / 32],
                                               int l15, int l4, int wr, int wc) {
    constexpr int MI = BM / 32, NJ = BN / 32;
    #pragma unroll
    for (int kk = 0; kk < 2; ++kk) {
        bf16x8 af[MI], bfr[NJ];
        int kByte = kk * 64 + l4 * 16;
        #pragma unroll
        for (int i = 0; i < MI; ++i) {
            int r = wr + i * 16 + l15;
            af[i] = *(const bf16x8*)(cA + r * 128 + (kByte ^ ((r & 7) << 4)));
        }
        #pragma unroll
        for (int j = 0; j < NJ; ++j) {
            int r = wc + j * 16 + l15;
            bfr[j] = *(const bf16x8*)(cB + r * 128 + (kByte ^ ((r & 7) << 4)));
        }
        #pragma unroll
        for (int i = 0; i < MI; ++i)
            #pragma unroll
            for (int j = 0; j < NJ; ++j)
                acc[i][j] = __builtin_amdgcn_mfma_f32_16x16x32_bf16(af[i], bfr[j], acc[i][j], 0, 0, 0);
    }
}

template<int BM, int BN>
__device__ __forceinline__ void gemm_core_t(const unsigned short* __restrict__ A,
                                            const unsigned short* __restrict__ Bw,
                                            int K, int bm, int bn,
                                            unsigned short* lsA, unsigned short* lsB,
                                            f32x4 acc[BM / 32][BN / 32]) {
    int t = threadIdx.x, lane = t & 63, w = t >> 6;
    int l15 = lane & 15, l4 = lane >> 4;
    int wr = (w >> 1) * (BM / 2), wc = (w & 1) * (BN / 2);
    const unsigned short* Abase = A + (size_t)(bm * BM) * K;
    const unsigned short* Bbase = Bw + (size_t)(bn * BN) * K;
    int nt = K >> 6;

    stage_tile_t<BM, BN>(Abase, Bbase, 0, K, 0, lsA, lsB, w, lane);
    for (int tq = 0; tq < nt - 1; ++tq) {
        int cur = tq & 1;
        stage_tile_t<BM, BN>(Abase, Bbase, (tq + 1) << 6, K, cur ^ 1, lsA, lsB, w, lane);
        if constexpr (BM / 32 + BN / 32 == 8)
            asm volatile("s_waitcnt vmcnt(8)" ::: "memory");   // cur done; next 8 in flight
        else
            asm volatile("s_waitcnt vmcnt(4)" ::: "memory");   // cur done; next 4 in flight
        __builtin_amdgcn_s_barrier();
        gemm_compute_t<BM, BN>((const char*)lsA + cur * (BM * 128),
                               (const char*)lsB + cur * (BN * 128), acc, l15, l4, wr, wc);
        asm volatile("s_waitcnt lgkmcnt(0)" ::: "memory");
        __builtin_amdgcn_s_barrier();
    }
    int cur = (nt - 1) & 1;
    asm volatile("s_waitcnt vmcnt(0)" ::: "memory");
    __builtin_amdgcn_s_barrier();
    gemm_compute_t<BM, BN>((const char*)lsA + cur * (BM * 128),
                           (const char*)lsB + cur * (BN * 128), acc, l15, l4, wr, wc);
}

// standard epilogue GEMM (res fp32, optional relu, fp32/bf16 out)
template<int BM, int BN, int RES, int RELU, int OUTBF>
__global__ __launch_bounds__(256) void k_gemm_t(const unsigned short* __restrict__ A,
                                                const unsigned short* __restrict__ Bw,
                                                const float* __restrict__ res,
                                                void* __restrict__ C, int N, int K) {
    __shared__ __align__(16) unsigned short lsA[2 * BM * 64];
    __shared__ __align__(16) unsigned short lsB[2 * BN * 64];
    f32x4 acc[BM / 32][BN / 32] = {};
    int bm = blockIdx.x, bn = blockIdx.y;
    gemm_core_t<BM, BN>(A, Bw, K, bm, bn, lsA, lsB, acc);
    int t = threadIdx.x, lane = t & 63, w = t >> 6;
    int l15 = lane & 15, l4 = lane >> 4;
    int wr = (w >> 1) * (BM / 2), wc = (w & 1) * (BN / 2);
    #pragma unroll
    for (int i = 0; i < BM / 32; ++i) {
        #pragma unroll
        for (int r = 0; r < 4; ++r) {
            int row = bm * BM + wr + i * 16 + l4 * 4 + r;
            #pragma unroll
            for (int j = 0; j < BN / 32; ++j) {
                int col = bn * BN + wc + j * 16 + l15;
                float v = acc[i][j][r];
                if (RES)  v += res[(size_t)row * N + col];
                if (RELU) v = fmaxf(v, 0.f);
                if (OUTBF) ((unsigned short*)C)[(size_t)row * N + col] = f2bf(v);
                else       ((float*)C)[(size_t)row * N + col] = v;
            }
        }
    }
}

// QKV: z=0 -> q (bf16 [B,S,768]), z=1 -> k (same), z=2 -> V^T bf16 [B*H, 64, 512]
__global__ __launch_bounds__(256) void k_gemm_qkv_bf(const unsigned short* __restrict__ X,
                                                     const unsigned short* __restrict__ wq,
                                                     const unsigned short* __restrict__ wk,
                                                     const unsigned short* __restrict__ wv,
                                                     unsigned short* __restrict__ qo,
                                                     unsigned short* __restrict__ ko,
                                                     unsigned short* __restrict__ vt) {
    __shared__ __align__(16) unsigned short lsA[2 * 128 * 64];
    __shared__ __align__(16) unsigned short lsB[2 * 128 * 64];
    f32x4 acc[4][4] = {};
    int z = blockIdx.z;
    const unsigned short* Bm = z == 0 ? wq : (z == 1 ? wk : wv);
    int bm = blockIdx.x, bn = blockIdx.y;
    gemm_core_t<128, 128>(X, Bm, D_, bm, bn, lsA, lsB, acc);
    int t = threadIdx.x, lane = t & 63, w = t >> 6;
    int l15 = lane & 15, l4 = lane >> 4;
    int wr = (w >> 1) * 64, wc = (w & 1) * 64;
    if (z < 2) {
        unsigned short* C = z == 0 ? qo : ko;
        #pragma unroll
        for (int i = 0; i < 4; ++i)
            #pragma unroll
            for (int r = 0; r < 4; ++r) {
                int row = bm * 128 + wr + i * 16 + l4 * 4 + r;
                #pragma unroll
                for (int j = 0; j < 4; ++j) {
                    int col = bn * 128 + wc + j * 16 + l15;
                    C[(size_t)row * D_ + col] = f2bf(acc[i][j][r]);
                }
            }
    } else {
        // V^T: vt[((b*H + h)*64 + dv)*512 + s], s = row%512, b = row/512
        #pragma unroll
        for (int i = 0; i < 4; ++i) {
            int row0 = bm * 128 + wr + i * 16 + l4 * 4;
            int b = row0 >> 9, s0 = row0 & 511;
            #pragma unroll
            for (int j = 0; j < 4; ++j) {
                int col = bn * 128 + wc + j * 16 + l15;
                int hh = col >> 6, dv = col & 63;
                ushort4 o4;
                o4.x = f2bf(acc[i][j][0]); o4.y = f2bf(acc[i][j][1]);
                o4.z = f2bf(acc[i][j][2]); o4.w = f2bf(acc[i][j][3]);
                *(ushort4*)(vt + (((size_t)b * H_ + hh) * 64 + dv) * S_ + s0) = o4;
            }
        }
    }
}

// ---------------- MFMA flash attention ----------------
__global__ __launch_bounds__(256) void k_attn_flash(const unsigned short* __restrict__ qb,
                                                    const unsigned short* __restrict__ kb,
                                                    const unsigned short* __restrict__ vtb,
                                                    const unsigned short* __restrict__ biasg,
                                                    const float* __restrict__ mask,
                                                    unsigned short* __restrict__ ctx) {
    __shared__ __align__(16) unsigned short Kt[64 * 64];
    __shared__ __align__(16) unsigned short Vt[64 * 64];
    __shared__ __align__(16) unsigned short Bt[64 * 64];
    __shared__ __align__(16) unsigned short Pt[4][16 * 64];

    int t = threadIdx.x, lane = t & 63, w = t >> 6;
    int l15 = lane & 15, l4 = lane >> 4;
    int bh = blockIdx.y;
    int b = bh / H_, hh = bh - b * H_;
    int qblk = blockIdx.x;
    int qloc = w * 16 + l15;
    int qg = qblk * 64 + qloc;

    bf16x8 qf[2];
    {
        const unsigned short* qp = qb + ((size_t)(b * S_ + qg)) * D_ + hh * DK_;
        qf[0] = *(const bf16x8*)(qp + l4 * 8);
        qf[1] = *(const bf16x8*)(qp + 32 + l4 * 8);
    }
    float mrun = -1e30f, lsum = 0.f;
    f32x4 cacc[4] = {};

    for (int kt = 0; kt < S_ / 64; ++kt) {
        int kbase = kt * 64;
        __syncthreads();
        #pragma unroll
        for (int c = 0; c < 2; ++c) {
            int off = (w * 2 + c) * 1024 + lane * 16;
            int row = off >> 7;
            int colb = (off & 127) ^ ((row & 7) << 4);
            GLDS(kb + ((size_t)(b * S_ + kbase + row)) * D_ + hh * DK_ + (colb >> 1),
                 (char*)Kt + off);
            GLDS(vtb + ((size_t)bh * 64 + row) * S_ + kbase + (colb >> 1),
                 (char*)Vt + off);
            GLDS(biasg + ((size_t)hh * S_ + qblk * 64 + row) * S_ + kbase + (colb >> 1),
                 (char*)Bt + off);
        }
        __syncthreads();

        f32x4 sc[4] = {};
        #pragma unroll
        for (int kk = 0; kk < 2; ++kk) {
            int kByte = kk * 64 + l4 * 16;
            #pragma unroll
            for (int j = 0; j < 4; ++j) {
                int r = j * 16 + l15;
                bf16x8 kf = *(const bf16x8*)((const char*)Kt + r * 128 + (kByte ^ ((r & 7) << 4)));
                sc[j] = __builtin_amdgcn_mfma_f32_16x16x32_bf16(kf, qf[kk], sc[j], 0, 0, 0);
            }
        }
        float sv[4][4];
        float tmax = -1e30f;
        #pragma unroll
        for (int j = 0; j < 4; ++j) {
            int bro = qloc * 128 + ((j * 32 + l4 * 8) ^ ((qloc & 7) << 4));
            ushort4 b4 = *(const ushort4*)((const char*)Bt + bro);
            float4 m4 = *(const float4*)(mask + (size_t)b * S_ + kbase + j * 16 + l4 * 4);
            sv[j][0] = sc[j][0] + bf2f(b4.x) + (1.f - m4.x) * NEG_;
            sv[j][1] = sc[j][1] + bf2f(b4.y) + (1.f - m4.y) * NEG_;
            sv[j][2] = sc[j][2] + bf2f(b4.z) + (1.f - m4.z) * NEG_;
            sv[j][3] = sc[j][3] + bf2f(b4.w) + (1.f - m4.w) * NEG_;
            tmax = fmaxf(tmax, fmaxf(fmaxf(sv[j][0], sv[j][1]), fmaxf(sv[j][2], sv[j][3])));
        }
        tmax = fmaxf(tmax, __shfl_xor(tmax, 16, 64));
        tmax = fmaxf(tmax, __shfl_xor(tmax, 32, 64));
        float mnew = fmaxf(mrun, tmax);
        float scal = __expf(mrun - mnew);
        #pragma unroll
        for (int i = 0; i < 4; ++i) {
            cacc[i][0] *= scal; cacc[i][1] *= scal;
            cacc[i][2] *= scal; cacc[i][3] *= scal;
        }
        float psum = 0.f;
        unsigned pp[8];
        #pragma unroll
        for (int j = 0; j < 4; ++j) {
            float p0 = __expf(sv[j][0] - mnew), p1 = __expf(sv[j][1] - mnew);
            float p2 = __expf(sv[j][2] - mnew), p3 = __expf(sv[j][3] - mnew);
            psum += (p0 + p1) + (p2 + p3);
            pp[j * 2]     = (unsigned)f2bf(p0) | ((unsigned)f2bf(p1) << 16);
            pp[j * 2 + 1] = (unsigned)f2bf(p2) | ((unsigned)f2bf(p3) << 16);
        }
        lsum = lsum * scal + psum;
        mrun = mnew;
        unsigned short* P = Pt[w];
        #pragma unroll
        for (int j = 0; j < 4; ++j) {
            int base = l15 * 128 + ((j * 32 + l4 * 8) ^ ((l15 & 7) << 4));
            *(unsigned*)((char*)P + base) = pp[j * 2];
            *(unsigned*)((char*)P + base + 4) = pp[j * 2 + 1];
        }
        #pragma unroll
        for (int kk = 0; kk < 2; ++kk) {
            int kByte = kk * 64 + l4 * 16;
            bf16x8 pf = *(const bf16x8*)((const char*)P + l15 * 128 + (kByte ^ ((l15 & 7) << 4)));
            #pragma unroll
            for (int i = 0; i < 4; ++i) {
                int rr = i * 16 + l15;
                bf16x8 vf = *(const bf16x8*)((const char*)Vt + rr * 128 + (kByte ^ ((rr & 7) << 4)));
                cacc[i] = __builtin_amdgcn_mfma_f32_16x16x32_bf16(vf, pf, cacc[i], 0, 0, 0);
            }
        }
    }
    lsum += __shfl_xor(lsum, 16, 64);
    lsum += __shfl_xor(lsum, 32, 64);
    float inv = 1.f / lsum;
    unsigned short* cp = ctx + ((size_t)(b * S_ + qg)) * D_ + hh * DK_;
    #pragma unroll
    for (int i = 0; i < 4; ++i) {
        ushort4 o4;
        o4.x = f2bf(cacc[i][0] * inv); o4.y = f2bf(cacc[i][1] * inv);
        o4.z = f2bf(cacc[i][2] * inv); o4.w = f2bf(cacc[i][3] * inv);
        *(ushort4*)(cp + i * 16 + l4 * 4) = o4;
    }
}

// ---------------- launcher ----------------
extern "C" void kernel_launch(void* const* d_in, const int* in_sizes, int n_in,
                              void* d_out, int out_size, void* d_ws, size_t ws_size,
                              hipStream_t stream) {
    const int*   ids  = (const int*)d_in[0];
    const float* mask = (const float*)d_in[1];
    const float* ew   = (const float*)d_in[2];
    const float* ln1  = (const float*)d_in[3];
    const float* qw   = (const float*)d_in[4];
    const float* kw   = (const float*)d_in[5];
    const float* vw   = (const float*)d_in[6];
    const float* rbw  = (const float*)d_in[7];
    const float* ow   = (const float*)d_in[8];
    const float* ln2  = (const float*)d_in[9];
    const float* wiw  = (const float*)d_in[10];
    const float* wow  = (const float*)d_in[11];
    const float* flnw = (const float*)d_in[12];
    float* out = (float*)d_out;

    // ws layout (64.5 MB): h | biasg | wbuf | xbf(=ctxb) | qbB kbB vtb [+6.3MB] (ff aliases qbB..)
    char* p = (char*)d_ws;
    float* h = (float*)p;                        p += BSD_ * 4;
    unsigned short* biasg = (unsigned short*)p;  p += (size_t)H_ * S_ * S_ * 2;
    unsigned short* wbuf  = (unsigned short*)p;  p += (size_t)7077888 * 2;
    unsigned short* xbf   = (unsigned short*)p;  p += BSD_ * 2;
    unsigned short* ctxb  = xbf;                 // aliased: disjoint lifetimes
    unsigned short* qbB   = (unsigned short*)p;  p += BSD_ * 2;
    unsigned short* kbB   = (unsigned short*)p;  p += BSD_ * 2;
    unsigned short* vtb   = (unsigned short*)p;  p += BSD_ * 2;
    /* extra 6.3MB tail for ff */                p += BSD_ * 2;
    unsigned short* ff    = qbB;                 // 25.2MB spans qbB..tail, dead by FFN

    const unsigned short* wq  = wbuf;
    const unsigned short* wk  = wbuf + 589824;
    const unsigned short* wv  = wbuf + 1179648;
    const unsigned short* wo  = wbuf + 1769472;
    const unsigned short* wwi = wbuf + 2359296;
    const unsigned short* wwo = wbuf + 4718592;

    k_embed<<<BS_, 192, 0, stream>>>(ids, ew, h);
    k_posbias<<<(S_ * S_ + 255) / 256, 256, 0, stream>>>(rbw, biasg);

    for (int l = 0; l < L_; ++l) {
        k_wconv<<<3456, 256, 0, stream>>>(qw + (size_t)l * 589824, kw + (size_t)l * 589824,
                                          vw + (size_t)l * 589824, ow + (size_t)l * 589824,
                                          wiw + (size_t)l * 2359296, wow + (size_t)l * 2359296,
                                          wbuf);
        k_rmsnorm<1><<<BS_, 256, 0, stream>>>(h, ln1 + (size_t)l * D_, xbf);
        k_gemm_qkv_bf<<<dim3(BS_ / 128, D_ / 128, 3), 256, 0, stream>>>(
            xbf, wq, wk, wv, qbB, kbB, vtb);
        k_attn_flash<<<dim3(S_ / 64, B_ * H_), 256, 0, stream>>>(
            qbB, kbB, vtb, biasg, mask, ctxb);
        k_gemm_t<64, 64, 1, 0, 0><<<dim3(BS_ / 64, D_ / 64), 256, 0, stream>>>(
            ctxb, wo, h, h, D_, D_);
        k_rmsnorm<1><<<BS_, 256, 0, stream>>>(h, ln2 + (size_t)l * D_, xbf);
        k_gemm_t<128, 128, 0, 1, 1><<<dim3(BS_ / 128, DFF_ / 128), 256, 0, stream>>>(
            xbf, wwi, nullptr, ff, DFF_, D_);
        k_gemm_t<64, 64, 1, 0, 0><<<dim3(BS_ / 64, D_ / 64), 256, 0, stream>>>(
            ff, wwo, h, h, D_, DFF_);
    }
    k_rmsnorm<0><<<BS_, 256, 0, stream>>>(h, flnw, out);
}

// Round 6
// 878.980 us; speedup vs baseline: 10.4106x; 1.0646x over previous
//
#include <hip/hip_runtime.h>
#include <hip/hip_bf16.h>
#include <math.h>

#define L_ 6
#define D_ 768
#define H_ 12
#define DK_ 64
#define DFF_ 3072
#define NB_ 32
#define MAXDIST_ 128
#define B_ 8
#define S_ 512
#define NEG_ (-1e9f)
#define BS_ (B_*S_)            // 4096 rows
#define BSD_ ((size_t)BS_*D_)  // 3,145,728 elements
#define WLAYER_ 7077888        // weight elements per layer (4*589824 + 2*2359296)

typedef __bf16 bf16x8 __attribute__((ext_vector_type(8)));
typedef float f32x4 __attribute__((ext_vector_type(4)));

__device__ __forceinline__ unsigned short f2bf(float f) {
    unsigned u = __float_as_uint(f);
    u += 0x7fff + ((u >> 16) & 1);          // RNE
    return (unsigned short)(u >> 16);
}
__device__ __forceinline__ float bf2f(unsigned short s) {
    return __uint_as_float(((unsigned)s) << 16);
}

#define GLDS(g, l) __builtin_amdgcn_global_load_lds( \
    (const __attribute__((address_space(1))) void*)(const void*)(g), \
    (__attribute__((address_space(3))) void*)(void*)(l), 16, 0, 0)

// ---------------- embedding gather ----------------
__global__ __launch_bounds__(192) void k_embed(const int* __restrict__ ids,
                                               const float* __restrict__ ew,
                                               float* __restrict__ h) {
    int row = blockIdx.x;
    int id = ids[row];
    const float4* src = (const float4*)(ew + (size_t)id * D_);
    float4* dst = (float4*)(h + (size_t)row * D_);
    dst[threadIdx.x] = src[threadIdx.x];
}

// ---------------- T5 RMSNorm ----------------
template<int OUTBF>
__global__ __launch_bounds__(256) void k_rmsnorm(const float* __restrict__ in,
                                                 const float* __restrict__ w,
                                                 void* __restrict__ outp) {
    int row = blockIdx.x;
    int tid = threadIdx.x;
    const float* x = in + (size_t)row * D_;
    float ss = 0.f;
    for (int i = tid; i < D_; i += 256) { float v = x[i]; ss += v * v; }
    #pragma unroll
    for (int off = 32; off; off >>= 1) ss += __shfl_down(ss, off, 64);
    __shared__ float sbuf[4];
    if ((tid & 63) == 0) sbuf[tid >> 6] = ss;
    __syncthreads();
    float tot = sbuf[0] + sbuf[1] + sbuf[2] + sbuf[3];
    float scale = rsqrtf(tot / (float)D_ + 1e-6f);
    if (OUTBF) {
        unsigned short* o = (unsigned short*)outp + (size_t)row * D_;
        for (int i = tid; i < D_; i += 256) o[i] = f2bf(w[i] * x[i] * scale);
    } else {
        float* o = (float*)outp + (size_t)row * D_;
        for (int i = tid; i < D_; i += 256) o[i] = w[i] * x[i] * scale;
    }
}

// ---------------- relative position bias, [h][q][key] bf16 ----------------
__global__ __launch_bounds__(256) void k_posbias(const float* __restrict__ rbw,
                                                 unsigned short* __restrict__ biasg) {
    int idx = blockIdx.x * 256 + threadIdx.x;
    if (idx >= S_ * S_) return;
    int q = idx / S_, key = idx - q * S_;
    int rel = key - q;                           // memory - query
    const int nb = NB_ / 2;                      // 16
    int ret = rel > 0 ? nb : 0;
    int n = rel < 0 ? -rel : rel;
    const int max_exact = nb / 2;                // 8
    int val;
    if (n < max_exact) {
        val = n;
    } else {
        float lf = logf((float)n / (float)max_exact) /
                   logf((float)MAXDIST_ / (float)max_exact) * (float)(nb - max_exact);
        val = max_exact + (int)lf;
        if (val > nb - 1) val = nb - 1;
    }
    int bucket = ret + val;
    #pragma unroll
    for (int hh = 0; hh < H_; ++hh)
        biasg[((size_t)hh * S_ + q) * S_ + key] = f2bf(rbw[bucket * H_ + hh]);
}

// ---------------- ALL layers weight fp32 -> bf16 (hoisted, one dispatch) ----------------
#define W1V8 73728    // 589824/8
#define W2V8 294912   // 2359296/8
#define WLV8 884736   // WLAYER_/8
__global__ __launch_bounds__(256) void k_wconv_all(const float* __restrict__ qw,
                                                   const float* __restrict__ kw,
                                                   const float* __restrict__ vw,
                                                   const float* __restrict__ ow,
                                                   const float* __restrict__ wiw,
                                                   const float* __restrict__ wow,
                                                   unsigned short* __restrict__ wb) {
    int gid = blockIdx.x * 256 + threadIdx.x;     // over 6*WLV8
    int l = gid / WLV8;
    int i = gid - l * WLV8;
    const float* src;
    if (i < W1V8)                src = qw  + (size_t)l * 589824;
    else if ((i -= W1V8) < W1V8) src = kw  + (size_t)l * 589824;
    else if ((i -= W1V8) < W1V8) src = vw  + (size_t)l * 589824;
    else if ((i -= W1V8) < W1V8) src = ow  + (size_t)l * 589824;
    else if ((i -= W1V8) < W2V8) src = wiw + (size_t)l * 2359296;
    else { i -= W2V8;            src = wow + (size_t)l * 2359296; }
    const float4* s4 = (const float4*)src + (size_t)i * 2;
    float4 a = s4[0], b = s4[1];
    ushort4 lo, hi;
    lo.x = f2bf(a.x); lo.y = f2bf(a.y); lo.z = f2bf(a.z); lo.w = f2bf(a.w);
    hi.x = f2bf(b.x); hi.y = f2bf(b.y); hi.z = f2bf(b.z); hi.w = f2bf(b.w);
    ushort4* d = (ushort4*)(wb + (size_t)gid * 8);
    d[0] = lo; d[1] = hi;
}

// ---------------- templated double-buffered MFMA GEMM core (BMxBN, BK=64, NT) ----------------
// 4 waves as 2x2; wave sub-tile (BM/2)x(BN/2). 2-phase: stage(next)->vmcnt(n)->bar->mfma->bar.
template<int BM, int BN>
__device__ __forceinline__ void stage_tile_t(const unsigned short* __restrict__ Abase,
                                             const unsigned short* __restrict__ Bbase,
                                             int k0, int K, int buf,
                                             unsigned short* lsA, unsigned short* lsB,
                                             int w, int lane) {
    constexpr int CA = BM / 32, CB = BN / 32;
    #pragma unroll
    for (int c = 0; c < CA; ++c) {
        int off = c * 4096 + w * 1024 + lane * 16;     // byte offset in BM*128 half-tile
        int row = off >> 7;
        int sc = (off & 127) ^ ((row & 7) << 4);       // pre-swizzled source col (bytes)
        GLDS(Abase + (size_t)row * K + k0 + (sc >> 1), (char*)lsA + buf * (BM * 128) + off);
    }
    #pragma unroll
    for (int c = 0; c < CB; ++c) {
        int off = c * 4096 + w * 1024 + lane * 16;
        int row = off >> 7;
        int sc = (off & 127) ^ ((row & 7) << 4);
        GLDS(Bbase + (size_t)row * K + k0 + (sc >> 1), (char*)lsB + buf * (BN * 128) + off);
    }
}

template<int BM, int BN>
__device__ __forceinline__ void gemm_compute_t(const char* cA, const char* cB,
                                               f32x4 acc[BM / 32][BN / 32],
                                               int l15, int l4, int wr, int wc) {
    constexpr int MI = BM / 32, NJ = BN / 32;
    #pragma unroll
    for (int kk = 0; kk < 2; ++kk) {
        bf16x8 af[MI], bfr[NJ];
        int kByte = kk * 64 + l4 * 16;
        #pragma unroll
        for (int i = 0; i < MI; ++i) {
            int r = wr + i * 16 + l15;
            af[i] = *(const bf16x8*)(cA + r * 128 + (kByte ^ ((r & 7) << 4)));
        }
        #pragma unroll
        for (int j = 0; j < NJ; ++j) {
            int r = wc + j * 16 + l15;
            bfr[j] = *(const bf16x8*)(cB + r * 128 + (kByte ^ ((r & 7) << 4)));
        }
        #pragma unroll
        for (int i = 0; i < MI; ++i)
            #pragma unroll
            for (int j = 0; j < NJ; ++j)
                acc[i][j] = __builtin_amdgcn_mfma_f32_16x16x32_bf16(af[i], bfr[j], acc[i][j], 0, 0, 0);
    }
}

template<int BM, int BN>
__device__ __forceinline__ void gemm_core_t(const unsigned short* __restrict__ A,
                                            const unsigned short* __restrict__ Bw,
                                            int K, int bm, int bn,
                                            unsigned short* lsA, unsigned short* lsB,
                                            f32x4 acc[BM / 32][BN / 32]) {
    int t = threadIdx.x, lane = t & 63, w = t >> 6;
    int l15 = lane & 15, l4 = lane >> 4;
    int wr = (w >> 1) * (BM / 2), wc = (w & 1) * (BN / 2);
    const unsigned short* Abase = A + (size_t)(bm * BM) * K;
    const unsigned short* Bbase = Bw + (size_t)(bn * BN) * K;
    int nt = K >> 6;
    constexpr int NL = BM / 32 + BN / 32;   // loads per stage

    stage_tile_t<BM, BN>(Abase, Bbase, 0, K, 0, lsA, lsB, w, lane);
    for (int tq = 0; tq < nt - 1; ++tq) {
        int cur = tq & 1;
        stage_tile_t<BM, BN>(Abase, Bbase, (tq + 1) << 6, K, cur ^ 1, lsA, lsB, w, lane);
        if constexpr (NL == 8)      asm volatile("s_waitcnt vmcnt(8)" ::: "memory");
        else if constexpr (NL == 6) asm volatile("s_waitcnt vmcnt(6)" ::: "memory");
        else                        asm volatile("s_waitcnt vmcnt(4)" ::: "memory");
        __builtin_amdgcn_s_barrier();
        gemm_compute_t<BM, BN>((const char*)lsA + cur * (BM * 128),
                               (const char*)lsB + cur * (BN * 128), acc, l15, l4, wr, wc);
        asm volatile("s_waitcnt lgkmcnt(0)" ::: "memory");
        __builtin_amdgcn_s_barrier();
    }
    int cur = (nt - 1) & 1;
    asm volatile("s_waitcnt vmcnt(0)" ::: "memory");
    __builtin_amdgcn_s_barrier();
    gemm_compute_t<BM, BN>((const char*)lsA + cur * (BM * 128),
                           (const char*)lsB + cur * (BN * 128), acc, l15, l4, wr, wc);
}

// standard epilogue GEMM (res fp32, optional relu, fp32/bf16 out)
template<int BM, int BN, int RES, int RELU, int OUTBF>
__global__ __launch_bounds__(256) void k_gemm_t(const unsigned short* __restrict__ A,
                                                const unsigned short* __restrict__ Bw,
                                                const float* __restrict__ res,
                                                void* __restrict__ C, int N, int K) {
    __shared__ __align__(16) unsigned short lsA[2 * BM * 64];
    __shared__ __align__(16) unsigned short lsB[2 * BN * 64];
    f32x4 acc[BM / 32][BN / 32] = {};
    int bm = blockIdx.x, bn = blockIdx.y;
    gemm_core_t<BM, BN>(A, Bw, K, bm, bn, lsA, lsB, acc);
    int t = threadIdx.x, lane = t & 63, w = t >> 6;
    int l15 = lane & 15, l4 = lane >> 4;
    int wr = (w >> 1) * (BM / 2), wc = (w & 1) * (BN / 2);
    #pragma unroll
    for (int i = 0; i < BM / 32; ++i) {
        #pragma unroll
        for (int r = 0; r < 4; ++r) {
            int row = bm * BM + wr + i * 16 + l4 * 4 + r;
            #pragma unroll
            for (int j = 0; j < BN / 32; ++j) {
                int col = bn * BN + wc + j * 16 + l15;
                float v = acc[i][j][r];
                if (RES)  v += res[(size_t)row * N + col];
                if (RELU) v = fmaxf(v, 0.f);
                if (OUTBF) ((unsigned short*)C)[(size_t)row * N + col] = f2bf(v);
                else       ((float*)C)[(size_t)row * N + col] = v;
            }
        }
    }
}

// QKV (64x128 tile): z=0 -> q bf16 [B,S,768], z=1 -> k, z=2 -> V^T bf16 [B*H, 64, 512]
__global__ __launch_bounds__(256) void k_gemm_qkv_bf(const unsigned short* __restrict__ X,
                                                     const unsigned short* __restrict__ wq,
                                                     const unsigned short* __restrict__ wk,
                                                     const unsigned short* __restrict__ wv,
                                                     unsigned short* __restrict__ qo,
                                                     unsigned short* __restrict__ ko,
                                                     unsigned short* __restrict__ vt) {
    __shared__ __align__(16) unsigned short lsA[2 * 64 * 64];
    __shared__ __align__(16) unsigned short lsB[2 * 128 * 64];
    f32x4 acc[2][4] = {};
    int z = blockIdx.z;
    const unsigned short* Bm = z == 0 ? wq : (z == 1 ? wk : wv);
    int bm = blockIdx.x, bn = blockIdx.y;
    gemm_core_t<64, 128>(X, Bm, D_, bm, bn, lsA, lsB, acc);
    int t = threadIdx.x, lane = t & 63, w = t >> 6;
    int l15 = lane & 15, l4 = lane >> 4;
    int wr = (w >> 1) * 32, wc = (w & 1) * 64;
    if (z < 2) {
        unsigned short* C = z == 0 ? qo : ko;
        #pragma unroll
        for (int i = 0; i < 2; ++i)
            #pragma unroll
            for (int r = 0; r < 4; ++r) {
                int row = bm * 64 + wr + i * 16 + l4 * 4 + r;
                #pragma unroll
                for (int j = 0; j < 4; ++j) {
                    int col = bn * 128 + wc + j * 16 + l15;
                    C[(size_t)row * D_ + col] = f2bf(acc[i][j][r]);
                }
            }
    } else {
        // V^T: vt[((b*H + h)*64 + dv)*512 + s]
        #pragma unroll
        for (int i = 0; i < 2; ++i) {
            int row0 = bm * 64 + wr + i * 16 + l4 * 4;
            int b = row0 >> 9, s0 = row0 & 511;
            #pragma unroll
            for (int j = 0; j < 4; ++j) {
                int col = bn * 128 + wc + j * 16 + l15;
                int hh = col >> 6, dv = col & 63;
                ushort4 o4;
                o4.x = f2bf(acc[i][j][0]); o4.y = f2bf(acc[i][j][1]);
                o4.z = f2bf(acc[i][j][2]); o4.w = f2bf(acc[i][j][3]);
                *(ushort4*)(vt + (((size_t)b * H_ + hh) * 64 + dv) * S_ + s0) = o4;
            }
        }
    }
}

// ---------------- MFMA flash attention ----------------
__global__ __launch_bounds__(256) void k_attn_flash(const unsigned short* __restrict__ qb,
                                                    const unsigned short* __restrict__ kb,
                                                    const unsigned short* __restrict__ vtb,
                                                    const unsigned short* __restrict__ biasg,
                                                    const float* __restrict__ mask,
                                                    unsigned short* __restrict__ ctx) {
    __shared__ __align__(16) unsigned short Kt[64 * 64];
    __shared__ __align__(16) unsigned short Vt[64 * 64];
    __shared__ __align__(16) unsigned short Bt[64 * 64];
    __shared__ __align__(16) unsigned short Pt[4][16 * 64];

    int t = threadIdx.x, lane = t & 63, w = t >> 6;
    int l15 = lane & 15, l4 = lane >> 4;
    int bh = blockIdx.y;
    int b = bh / H_, hh = bh - b * H_;
    int qblk = blockIdx.x;
    int qloc = w * 16 + l15;
    int qg = qblk * 64 + qloc;

    bf16x8 qf[2];
    {
        const unsigned short* qp = qb + ((size_t)(b * S_ + qg)) * D_ + hh * DK_;
        qf[0] = *(const bf16x8*)(qp + l4 * 8);
        qf[1] = *(const bf16x8*)(qp + 32 + l4 * 8);
    }
    float mrun = -1e30f, lsum = 0.f;
    f32x4 cacc[4] = {};

    for (int kt = 0; kt < S_ / 64; ++kt) {
        int kbase = kt * 64;
        __syncthreads();
        #pragma unroll
        for (int c = 0; c < 2; ++c) {
            int off = (w * 2 + c) * 1024 + lane * 16;
            int row = off >> 7;
            int colb = (off & 127) ^ ((row & 7) << 4);
            GLDS(kb + ((size_t)(b * S_ + kbase + row)) * D_ + hh * DK_ + (colb >> 1),
                 (char*)Kt + off);
            GLDS(vtb + ((size_t)bh * 64 + row) * S_ + kbase + (colb >> 1),
                 (char*)Vt + off);
            GLDS(biasg + ((size_t)hh * S_ + qblk * 64 + row) * S_ + kbase + (colb >> 1),
                 (char*)Bt + off);
        }
        __syncthreads();

        f32x4 sc[4] = {};
        #pragma unroll
        for (int kk = 0; kk < 2; ++kk) {
            int kByte = kk * 64 + l4 * 16;
            #pragma unroll
            for (int j = 0; j < 4; ++j) {
                int r = j * 16 + l15;
                bf16x8 kf = *(const bf16x8*)((const char*)Kt + r * 128 + (kByte ^ ((r & 7) << 4)));
                sc[j] = __builtin_amdgcn_mfma_f32_16x16x32_bf16(kf, qf[kk], sc[j], 0, 0, 0);
            }
        }
        float sv[4][4];
        float tmax = -1e30f;
        #pragma unroll
        for (int j = 0; j < 4; ++j) {
            int bro = qloc * 128 + ((j * 32 + l4 * 8) ^ ((qloc & 7) << 4));
            ushort4 b4 = *(const ushort4*)((const char*)Bt + bro);
            float4 m4 = *(const float4*)(mask + (size_t)b * S_ + kbase + j * 16 + l4 * 4);
            sv[j][0] = sc[j][0] + bf2f(b4.x) + (1.f - m4.x) * NEG_;
            sv[j][1] = sc[j][1] + bf2f(b4.y) + (1.f - m4.y) * NEG_;
            sv[j][2] = sc[j][2] + bf2f(b4.z) + (1.f - m4.z) * NEG_;
            sv[j][3] = sc[j][3] + bf2f(b4.w) + (1.f - m4.w) * NEG_;
            tmax = fmaxf(tmax, fmaxf(fmaxf(sv[j][0], sv[j][1]), fmaxf(sv[j][2], sv[j][3])));
        }
        tmax = fmaxf(tmax, __shfl_xor(tmax, 16, 64));
        tmax = fmaxf(tmax, __shfl_xor(tmax, 32, 64));
        float mnew = fmaxf(mrun, tmax);
        float scal = __expf(mrun - mnew);
        #pragma unroll
        for (int i = 0; i < 4; ++i) {
            cacc[i][0] *= scal; cacc[i][1] *= scal;
            cacc[i][2] *= scal; cacc[i][3] *= scal;
        }
        float psum = 0.f;
        unsigned pp[8];
        #pragma unroll
        for (int j = 0; j < 4; ++j) {
            float p0 = __expf(sv[j][0] - mnew), p1 = __expf(sv[j][1] - mnew);
            float p2 = __expf(sv[j][2] - mnew), p3 = __expf(sv[j][3] - mnew);
            psum += (p0 + p1) + (p2 + p3);
            pp[j * 2]     = (unsigned)f2bf(p0) | ((unsigned)f2bf(p1) << 16);
            pp[j * 2 + 1] = (unsigned)f2bf(p2) | ((unsigned)f2bf(p3) << 16);
        }
        lsum = lsum * scal + psum;
        mrun = mnew;
        unsigned short* P = Pt[w];
        #pragma unroll
        for (int j = 0; j < 4; ++j) {
            int base = l15 * 128 + ((j * 32 + l4 * 8) ^ ((l15 & 7) << 4));
            *(unsigned*)((char*)P + base) = pp[j * 2];
            *(unsigned*)((char*)P + base + 4) = pp[j * 2 + 1];
        }
        #pragma unroll
        for (int kk = 0; kk < 2; ++kk) {
            int kByte = kk * 64 + l4 * 16;
            bf16x8 pf = *(const bf16x8*)((const char*)P + l15 * 128 + (kByte ^ ((l15 & 7) << 4)));
            #pragma unroll
            for (int i = 0; i < 4; ++i) {
                int rr = i * 16 + l15;
                bf16x8 vf = *(const bf16x8*)((const char*)Vt + rr * 128 + (kByte ^ ((rr & 7) << 4)));
                cacc[i] = __builtin_amdgcn_mfma_f32_16x16x32_bf16(vf, pf, cacc[i], 0, 0, 0);
            }
        }
    }
    lsum += __shfl_xor(lsum, 16, 64);
    lsum += __shfl_xor(lsum, 32, 64);
    float inv = 1.f / lsum;
    unsigned short* cp = ctx + ((size_t)(b * S_ + qg)) * D_ + hh * DK_;
    #pragma unroll
    for (int i = 0; i < 4; ++i) {
        ushort4 o4;
        o4.x = f2bf(cacc[i][0] * inv); o4.y = f2bf(cacc[i][1] * inv);
        o4.z = f2bf(cacc[i][2] * inv); o4.w = f2bf(cacc[i][3] * inv);
        *(ushort4*)(cp + i * 16 + l4 * 4) = o4;
    }
}

// ---------------- launcher ----------------
extern "C" void kernel_launch(void* const* d_in, const int* in_sizes, int n_in,
                              void* d_out, int out_size, void* d_ws, size_t ws_size,
                              hipStream_t stream) {
    const int*   ids  = (const int*)d_in[0];
    const float* mask = (const float*)d_in[1];
    const float* ew   = (const float*)d_in[2];
    const float* ln1  = (const float*)d_in[3];
    const float* qw   = (const float*)d_in[4];
    const float* kw   = (const float*)d_in[5];
    const float* vw   = (const float*)d_in[6];
    const float* rbw  = (const float*)d_in[7];
    const float* ow   = (const float*)d_in[8];
    const float* ln2  = (const float*)d_in[9];
    const float* wiw  = (const float*)d_in[10];
    const float* wow  = (const float*)d_in[11];
    const float* flnw = (const float*)d_in[12];
    float* out = (float*)d_out;

    // ws layout (~136 MB of ~385 MB): h | biasg | wball(6 layers) | xbf(=ctxb) | qbB kbB vtb [+tail]
    char* p = (char*)d_ws;
    float* h = (float*)p;                        p += BSD_ * 4;
    unsigned short* biasg = (unsigned short*)p;  p += (size_t)H_ * S_ * S_ * 2;
    unsigned short* wball = (unsigned short*)p;  p += (size_t)L_ * WLAYER_ * 2;
    unsigned short* xbf   = (unsigned short*)p;  p += BSD_ * 2;
    unsigned short* ctxb  = xbf;                 // aliased: disjoint lifetimes
    unsigned short* qbB   = (unsigned short*)p;  p += BSD_ * 2;
    unsigned short* kbB   = (unsigned short*)p;  p += BSD_ * 2;
    unsigned short* vtb   = (unsigned short*)p;  p += BSD_ * 2;
    /* extra 6.3MB tail for ff */                p += BSD_ * 2;
    unsigned short* ff    = qbB;                 // 25.2MB spans qbB..tail, dead by FFN

    k_embed<<<BS_, 192, 0, stream>>>(ids, ew, h);
    k_posbias<<<(S_ * S_ + 255) / 256, 256, 0, stream>>>(rbw, biasg);
    k_wconv_all<<<(L_ * WLV8) / 256, 256, 0, stream>>>(qw, kw, vw, ow, wiw, wow, wball);

    for (int l = 0; l < L_; ++l) {
        const unsigned short* wl  = wball + (size_t)l * WLAYER_;
        const unsigned short* wq  = wl;
        const unsigned short* wk  = wl + 589824;
        const unsigned short* wv  = wl + 1179648;
        const unsigned short* wo  = wl + 1769472;
        const unsigned short* wwi = wl + 2359296;
        const unsigned short* wwo = wl + 4718592;

        k_rmsnorm<1><<<BS_, 256, 0, stream>>>(h, ln1 + (size_t)l * D_, xbf);
        k_gemm_qkv_bf<<<dim3(BS_ / 64, D_ / 128, 3), 256, 0, stream>>>(
            xbf, wq, wk, wv, qbB, kbB, vtb);
        k_attn_flash<<<dim3(S_ / 64, B_ * H_), 256, 0, stream>>>(
            qbB, kbB, vtb, biasg, mask, ctxb);
        k_gemm_t<64, 64, 1, 0, 0><<<dim3(BS_ / 64, D_ / 64), 256, 0, stream>>>(
            ctxb, wo, h, h, D_, D_);
        k_rmsnorm<1><<<BS_, 256, 0, stream>>>(h, ln2 + (size_t)l * D_, xbf);
        k_gemm_t<64, 128, 0, 1, 1><<<dim3(BS_ / 64, DFF_ / 128), 256, 0, stream>>>(
            xbf, wwi, nullptr, ff, DFF_, D_);
        k_gemm_t<64, 64, 1, 0, 0><<<dim3(BS_ / 64, D_ / 64), 256, 0, stream>>>(
            ff, wwo, h, h, D_, DFF_);
    }
    k_rmsnorm<0><<<BS_, 256, 0, stream>>>(h, flnw, out);
}